// Round 1
// baseline (257.557 us; speedup 1.0000x reference)
//
#include <hip/hip_runtime.h>

// MHA: out = softmax((xWq^T+bq)(xWk^T+bk)^T / sqrt(64)) (xWv^T+bv) Wo^T + bo
// B=2, L=2048, D=1024, H=16, Hd=64. bf16 MFMA pipeline, fp32 accum.

typedef __attribute__((ext_vector_type(4))) float f32x4;
typedef __attribute__((ext_vector_type(4))) unsigned int u32x4;
typedef __attribute__((ext_vector_type(8))) short bf16x8;

#define DEVI static __device__ __forceinline__

DEVI unsigned short f2bf(float x) {  // round-to-nearest-even fp32 -> bf16
  union { float f; unsigned u; } v; v.f = x;
  unsigned r = v.u + 0x7fffu + ((v.u >> 16) & 1u);
  return (unsigned short)(r >> 16);
}

DEVI void gload_lds16(const void* g, void* l) {
  __builtin_amdgcn_global_load_lds((__attribute__((address_space(1))) void*)g,
                                   (__attribute__((address_space(3))) void*)l, 16, 0, 0);
}

constexpr int MD = 1024;
constexpr int NH = 16;
constexpr int HD = 64;
constexpr int LL = 2048;

// ---------------- fp32 -> bf16 weight convert (1M elems per launch) ------------
__global__ void cvt_w_kernel(const float* __restrict__ w, unsigned short* __restrict__ o) {
  int i = (blockIdx.x * 256 + threadIdx.x) * 8;
  f32x4 a = *(const f32x4*)(w + i);
  f32x4 b = *(const f32x4*)(w + i + 4);
  union { unsigned short us[8]; u32x4 u; } r;
  r.us[0] = f2bf(a[0]); r.us[1] = f2bf(a[1]); r.us[2] = f2bf(a[2]); r.us[3] = f2bf(a[3]);
  r.us[4] = f2bf(b[0]); r.us[5] = f2bf(b[1]); r.us[6] = f2bf(b[2]); r.us[7] = f2bf(b[3]);
  *(u32x4*)(o + i) = r.u;
}

// ---------------- GEMM: C[m][n] = sum_k A[m][k]*W[n][k] + bias[n] --------------
// MODE 0: A fp32, out bf16 -> Qh[b][h][l][d] scaled by 0.125
// MODE 1: A fp32, out bf16 -> Kh[b][h][l][d]
// MODE 2: A fp32, out bf16 -> Vt[b][h][d][l]  (transposed for attention PV)
// MODE 3: A bf16 (ctx),  out fp32 [m][n] (d_out)
template<int MODE>
__global__ __launch_bounds__(256, 2) void gemm_bt(const void* __restrict__ Ain,
                                                  const unsigned short* __restrict__ Wb,
                                                  const float* __restrict__ bias,
                                                  void* __restrict__ Out) {
  constexpr int LDA = 40;  // padded LDS row stride (elems): 80B -> conflict-free b128 reads
  __shared__ alignas(16) unsigned short Al[2][128 * LDA];
  __shared__ alignas(16) unsigned short Bl[2][128 * LDA];

  const int tid = threadIdx.x;
  const int lane = tid & 63;
  const int wave = tid >> 6;
  const int wr = wave >> 1, wc = wave & 1;
  const int m0 = blockIdx.y * 128, n0 = blockIdx.x * 128;
  const int srow = tid >> 1, shalf = (tid & 1) * 16;
  const int lr = lane & 15, lg = lane >> 4;

  f32x4 acc[4][4] = {};
  f32x4 areg[4];
  u32x4 abreg[2];
  u32x4 wreg[2];

  const float* Af = (const float*)Ain;
  const unsigned short* Ab = (const unsigned short*)Ain;

  auto gload = [&](int kt) {
    const int k0 = kt * 32;
    if constexpr (MODE < 3) {
      const float* s = Af + (size_t)(m0 + srow) * 1024 + k0 + shalf;
      areg[0] = *(const f32x4*)(s);
      areg[1] = *(const f32x4*)(s + 4);
      areg[2] = *(const f32x4*)(s + 8);
      areg[3] = *(const f32x4*)(s + 12);
    } else {
      const unsigned int* s = (const unsigned int*)(Ab + (size_t)(m0 + srow) * 1024 + k0 + shalf);
      abreg[0] = *(const u32x4*)(s);
      abreg[1] = *(const u32x4*)(s + 4);
    }
    const unsigned int* wsrc = (const unsigned int*)(Wb + (size_t)(n0 + srow) * 1024 + k0 + shalf);
    wreg[0] = *(const u32x4*)(wsrc);
    wreg[1] = *(const u32x4*)(wsrc + 4);
  };

  auto swrite = [&](int buf) {
    union { unsigned short us[16]; u32x4 u[2]; } t;
    if constexpr (MODE < 3) {
      #pragma unroll
      for (int i = 0; i < 4; ++i) {
        t.us[i*4+0] = f2bf(areg[i][0]); t.us[i*4+1] = f2bf(areg[i][1]);
        t.us[i*4+2] = f2bf(areg[i][2]); t.us[i*4+3] = f2bf(areg[i][3]);
      }
    } else { t.u[0] = abreg[0]; t.u[1] = abreg[1]; }
    *(u32x4*)&Al[buf][srow * LDA + shalf]     = t.u[0];
    *(u32x4*)&Al[buf][srow * LDA + shalf + 8] = t.u[1];
    *(u32x4*)&Bl[buf][srow * LDA + shalf]     = wreg[0];
    *(u32x4*)&Bl[buf][srow * LDA + shalf + 8] = wreg[1];
  };

  gload(0);
  swrite(0);
  __syncthreads();

  for (int kt = 0; kt < 32; ++kt) {
    const int buf = kt & 1;
    if (kt < 31) gload(kt + 1);   // issue next-tile global loads; hide under MFMAs
    bf16x8 af[4], bfr[4];
    #pragma unroll
    for (int mi = 0; mi < 4; ++mi)
      af[mi] = *(const bf16x8*)&Al[buf][(wr * 64 + mi * 16 + lr) * LDA + lg * 8];
    #pragma unroll
    for (int ni = 0; ni < 4; ++ni)
      bfr[ni] = *(const bf16x8*)&Bl[buf][(wc * 64 + ni * 16 + lr) * LDA + lg * 8];
    #pragma unroll
    for (int mi = 0; mi < 4; ++mi)
      #pragma unroll
      for (int ni = 0; ni < 4; ++ni)
        acc[mi][ni] = __builtin_amdgcn_mfma_f32_16x16x32_bf16(af[mi], bfr[ni], acc[mi][ni], 0, 0, 0);
    if (kt < 31) swrite(buf ^ 1);
    __syncthreads();
  }

  float bv[4];
  const int cn = n0 + wc * 64 + lr;
  #pragma unroll
  for (int ni = 0; ni < 4; ++ni) bv[ni] = bias[cn + ni * 16];

  #pragma unroll
  for (int mi = 0; mi < 4; ++mi) {
    #pragma unroll
    for (int j = 0; j < 4; ++j) {
      const int m = m0 + wr * 64 + mi * 16 + lg * 4 + j;
      if constexpr (MODE == 3) {
        float* o = (float*)Out;
        #pragma unroll
        for (int ni = 0; ni < 4; ++ni)
          o[(size_t)m * 1024 + cn + ni * 16] = acc[mi][ni][j] + bv[ni];
      } else {
        unsigned short* o = (unsigned short*)Out;
        const int b = m >> 11, l = m & 2047;
        #pragma unroll
        for (int ni = 0; ni < 4; ++ni) {
          const int n = cn + ni * 16;
          const int h = n >> 6, d = n & 63;
          float val = acc[mi][ni][j] + bv[ni];
          if constexpr (MODE == 0) val *= 0.125f;   // fold 1/sqrt(Hd) into Q
          if constexpr (MODE == 2)
            o[((size_t)(b * NH + h) * HD + d) * LL + l] = f2bf(val);
          else
            o[((size_t)(b * NH + h) * LL + l) * HD + d] = f2bf(val);
        }
      }
    }
  }
}

// ---------------- flash attention ---------------------------------------------
// grid: x = L/64 q-blocks, y = B*H. 4 waves x 16 q-rows. KB=64 KV tiles,
// double-buffered global_load_lds with XOR-16B swizzle (pre-swizzled source).
__global__ __launch_bounds__(256, 2) void attn_kernel(const unsigned short* __restrict__ Qh,
                                                      const unsigned short* __restrict__ Kh,
                                                      const unsigned short* __restrict__ Vt,
                                                      unsigned short* __restrict__ Ctx) {
  constexpr int KB = 64;
  constexpr int NT = LL / KB;  // 32
  __shared__ alignas(16) unsigned short Kl[2][KB * HD];   // [kv][d]
  __shared__ alignas(16) unsigned short Vl[2][HD * KB];   // [d][kv]
  __shared__ alignas(16) unsigned short Pl[4][16 * KB];   // per-wave P

  const int tid = threadIdx.x;
  const int lane = tid & 63;
  const int wave = tid >> 6;
  const int lr = lane & 15, lg = lane >> 4;
  const int bh = blockIdx.y;
  const int q0 = blockIdx.x * 64 + wave * 16;

  const unsigned short* Kg = Kh + (size_t)bh * LL * HD;
  const unsigned short* Vg = Vt + (size_t)bh * HD * LL;

  bf16x8 qf[2];
  {
    const unsigned short* qp = Qh + (size_t)bh * LL * HD + (size_t)(q0 + lr) * HD + lg * 8;
    qf[0] = *(const bf16x8*)qp;
    qf[1] = *(const bf16x8*)(qp + 32);
  }

  float m_[4], s_[4];
  f32x4 cacc[4] = {};
  #pragma unroll
  for (int j = 0; j < 4; ++j) { m_[j] = -1e30f; s_[j] = 0.f; }

  auto stage = [&](int buf, int t) {
    #pragma unroll
    for (int p = 0; p < 2; ++p) {
      const int o0 = p * 4096 + wave * 1024;
      const int o = o0 + lane * 16;
      const int row = o >> 7;
      const int xs = (o & 127) ^ ((row & 7) << 4);
      gload_lds16((const char*)(Kg + (size_t)t * KB * HD) + row * 128 + xs,
                  (char*)&Kl[buf][0] + o0);
    }
    #pragma unroll
    for (int p = 0; p < 2; ++p) {
      const int o0 = p * 4096 + wave * 1024;
      const int o = o0 + lane * 16;
      const int row = o >> 7;
      const int xs = (o & 127) ^ ((row & 7) << 4);
      gload_lds16((const char*)(Vg + (size_t)t * KB) + (size_t)row * (LL * 2) + xs,
                  (char*)&Vl[buf][0] + o0);
    }
  };

  stage(0, 0);
  __syncthreads();

  for (int t = 0; t < NT; ++t) {
    const int buf = t & 1;
    if (t + 1 < NT) stage(buf ^ 1, t + 1);  // prefetch, drained by end-of-loop barrier

    // S = Q K^T  (scale pre-folded into Q); S acc: row=(lg*4+j) q, col=lr kv
    f32x4 sacc[4];
    #pragma unroll
    for (int c = 0; c < 4; ++c) {
      const int row = c * 16 + lr;
      const char* kl = (const char*)&Kl[buf][0] + row * 128;
      const int sw = (row & 7) << 4;
      bf16x8 k0 = *(const bf16x8*)(kl + ((lg * 16) ^ sw));
      bf16x8 k1 = *(const bf16x8*)(kl + ((64 + lg * 16) ^ sw));
      f32x4 s = {};
      s = __builtin_amdgcn_mfma_f32_16x16x32_bf16(qf[0], k0, s, 0, 0, 0);
      s = __builtin_amdgcn_mfma_f32_16x16x32_bf16(qf[1], k1, s, 0, 0, 0);
      sacc[c] = s;
    }

    // online softmax (row stats replicated across 16-lane groups)
    float pe[4][4];
    #pragma unroll
    for (int j = 0; j < 4; ++j) {
      float tm = fmaxf(fmaxf(sacc[0][j], sacc[1][j]), fmaxf(sacc[2][j], sacc[3][j]));
      tm = fmaxf(tm, __shfl_xor(tm, 1));
      tm = fmaxf(tm, __shfl_xor(tm, 2));
      tm = fmaxf(tm, __shfl_xor(tm, 4));
      tm = fmaxf(tm, __shfl_xor(tm, 8));
      const float nm = fmaxf(m_[j], tm);
      const float al = __expf(m_[j] - nm);
      float rs = 0.f;
      #pragma unroll
      for (int c = 0; c < 4; ++c) { const float e = __expf(sacc[c][j] - nm); pe[c][j] = e; rs += e; }
      rs += __shfl_xor(rs, 1); rs += __shfl_xor(rs, 2);
      rs += __shfl_xor(rs, 4); rs += __shfl_xor(rs, 8);
      s_[j] = s_[j] * al + rs;
      m_[j] = nm;
      #pragma unroll
      for (int dt = 0; dt < 4; ++dt) cacc[dt][j] *= al;
    }

    // P -> LDS (swizzled), then PV
    unsigned short* pb = &Pl[wave][0];
    #pragma unroll
    for (int j = 0; j < 4; ++j) {
      const int r = lg * 4 + j;
      const int sw = (r & 7) << 4;
      #pragma unroll
      for (int c = 0; c < 4; ++c)
        *(unsigned short*)((char*)pb + r * 128 + (((c * 16 + lr) * 2) ^ sw)) = f2bf(pe[c][j]);
    }
    asm volatile("s_waitcnt lgkmcnt(0)" ::: "memory");  // wave-internal write->read ordering

    {
      const int sw = (lr & 7) << 4;
      const char* pc = (const char*)pb + lr * 128;
      bf16x8 pf0 = *(const bf16x8*)(pc + ((lg * 16) ^ sw));
      bf16x8 pf1 = *(const bf16x8*)(pc + ((64 + lg * 16) ^ sw));
      #pragma unroll
      for (int dt = 0; dt < 4; ++dt) {
        const int vrow = dt * 16 + lr;
        const char* vl = (const char*)&Vl[buf][0] + vrow * 128;
        const int vsw = (vrow & 7) << 4;
        bf16x8 v0 = *(const bf16x8*)(vl + ((lg * 16) ^ vsw));
        bf16x8 v1 = *(const bf16x8*)(vl + ((64 + lg * 16) ^ vsw));
        cacc[dt] = __builtin_amdgcn_mfma_f32_16x16x32_bf16(pf0, v0, cacc[dt], 0, 0, 0);
        cacc[dt] = __builtin_amdgcn_mfma_f32_16x16x32_bf16(pf1, v1, cacc[dt], 0, 0, 0);
      }
    }
    __syncthreads();
  }

  // normalize + write ctx[b][l][h*64+d] (bf16)
  const int b = bh >> 4, h = bh & 15;
  #pragma unroll
  for (int dt = 0; dt < 4; ++dt) {
    #pragma unroll
    for (int j = 0; j < 4; ++j) {
      const int qq = q0 + lg * 4 + j;
      const int d = dt * 16 + lr;
      const float val = cacc[dt][j] / s_[j];
      Ctx[((size_t)(b * LL + qq)) * MD + h * HD + d] = f2bf(val);
    }
  }
}

extern "C" void kernel_launch(void* const* d_in, const int* in_sizes, int n_in,
                              void* d_out, int out_size, void* d_ws, size_t ws_size,
                              hipStream_t stream) {
  const float* q  = (const float*)d_in[0];
  const float* k  = (const float*)d_in[1];
  const float* v  = (const float*)d_in[2];
  const float* Wq = (const float*)d_in[3];
  const float* bq = (const float*)d_in[4];
  const float* Wk = (const float*)d_in[5];
  const float* bk = (const float*)d_in[6];
  const float* Wv = (const float*)d_in[7];
  const float* bv = (const float*)d_in[8];
  const float* Wo = (const float*)d_in[9];
  const float* bo = (const float*)d_in[10];

  char* ws = (char*)d_ws;
  const size_t MB = 1u << 20;
  unsigned short* Wqb = (unsigned short*)(ws + 0 * MB);
  unsigned short* Wkb = (unsigned short*)(ws + 2 * MB);
  unsigned short* Wvb = (unsigned short*)(ws + 4 * MB);
  unsigned short* Wob = (unsigned short*)(ws + 6 * MB);
  unsigned short* Qhb = (unsigned short*)(ws + 8 * MB);
  unsigned short* Khb = (unsigned short*)(ws + 16 * MB);
  unsigned short* Vtb = (unsigned short*)(ws + 24 * MB);
  unsigned short* ctx = (unsigned short*)(ws + 32 * MB);

  cvt_w_kernel<<<512, 256, 0, stream>>>(Wq, Wqb);
  cvt_w_kernel<<<512, 256, 0, stream>>>(Wk, Wkb);
  cvt_w_kernel<<<512, 256, 0, stream>>>(Wv, Wvb);
  cvt_w_kernel<<<512, 256, 0, stream>>>(Wo, Wob);

  dim3 g(8, 32);
  gemm_bt<0><<<g, 256, 0, stream>>>(q, Wqb, bq, Qhb);
  gemm_bt<1><<<g, 256, 0, stream>>>(k, Wkb, bk, Khb);
  gemm_bt<2><<<g, 256, 0, stream>>>(v, Wvb, bv, Vtb);

  attn_kernel<<<dim3(32, 32), 256, 0, stream>>>(Qhb, Khb, Vtb, ctx);

  gemm_bt<3><<<g, 256, 0, stream>>>(ctx, Wob, bo, d_out);
}

// Round 2
// 175.349 us; speedup vs baseline: 1.4688x; 1.4688x over previous
//
#include <hip/hip_runtime.h>

// MHA: out = softmax((xWq^T+bq)(xWk^T+bk)^T / sqrt(64)) (xWv^T+bv) Wo^T + bo
// B=2, L=2048, D=1024, H=16, Hd=64. bf16 MFMA pipeline, fp32 accum.
// Attention: swapped-QK 32x32 MFMA, in-register softmax (exp2 domain),
// cvt_pk + shfl cross-half exchange for P fragments, defer-max.

typedef __attribute__((ext_vector_type(4))) float f32x4;
typedef __attribute__((ext_vector_type(16))) float f32x16;
typedef __attribute__((ext_vector_type(4))) unsigned int u32x4;
typedef __attribute__((ext_vector_type(2))) unsigned int u32x2;
typedef __attribute__((ext_vector_type(8))) short bf16x8;

#define DEVI static __device__ __forceinline__

DEVI unsigned short f2bf(float x) {  // round-to-nearest-even fp32 -> bf16
  union { float f; unsigned u; } v; v.f = x;
  unsigned r = v.u + 0x7fffu + ((v.u >> 16) & 1u);
  return (unsigned short)(r >> 16);
}

DEVI unsigned cvtpk(float lo, float hi) {  // packed fp32x2 -> bf16x2
  unsigned r;
  asm("v_cvt_pk_bf16_f32 %0, %1, %2" : "=v"(r) : "v"(lo), "v"(hi));
  return r;
}

DEVI float exp2v(float x) {  // 2^x via v_exp_f32
  float y;
  asm("v_exp_f32 %0, %1" : "=v"(y) : "v"(x));
  return y;
}

DEVI void gload_lds16(const void* g, void* l) {
  __builtin_amdgcn_global_load_lds((__attribute__((address_space(1))) void*)g,
                                   (__attribute__((address_space(3))) void*)l, 16, 0, 0);
}

constexpr int MD = 1024;
constexpr int NH = 16;
constexpr int HD = 64;
constexpr int LL = 2048;
// fold 1/sqrt(64) * log2(e) into Q so softmax runs in exp2 domain
constexpr float CQ = 0.18033688011112042f;

// ---------------- fp32 -> bf16 weight convert (1M elems per launch) ------------
__global__ void cvt_w_kernel(const float* __restrict__ w, unsigned short* __restrict__ o) {
  int i = (blockIdx.x * 256 + threadIdx.x) * 8;
  f32x4 a = *(const f32x4*)(w + i);
  f32x4 b = *(const f32x4*)(w + i + 4);
  union { unsigned short us[8]; u32x4 u; } r;
  r.us[0] = f2bf(a[0]); r.us[1] = f2bf(a[1]); r.us[2] = f2bf(a[2]); r.us[3] = f2bf(a[3]);
  r.us[4] = f2bf(b[0]); r.us[5] = f2bf(b[1]); r.us[6] = f2bf(b[2]); r.us[7] = f2bf(b[3]);
  *(u32x4*)(o + i) = r.u;
}

// ---------------- fused QKV GEMM: C = A W^T + b, 3 modes by blockIdx.y ---------
// mode 0: Q -> Qh[b][h][l][d], scaled by CQ
// mode 1: K -> Kh[b][h][l][d]
// mode 2: V -> Vt[b][h][d][l]  (transposed for attention PV)
struct QKVArgs {
  const float* A[3];
  const unsigned short* W[3];
  const float* bias[3];
  unsigned short* out[3];
};

__global__ __launch_bounds__(256, 2) void gemm_qkv(QKVArgs args) {
  constexpr int LDA = 40;  // padded LDS stride: conflict-free b128 reads
  __shared__ alignas(16) unsigned short Al[2][128 * LDA];
  __shared__ alignas(16) unsigned short Bl[2][128 * LDA];

  const int tid = threadIdx.x;
  const int lane = tid & 63;
  const int wave = tid >> 6;
  const int wr = wave >> 1, wc = wave & 1;
  const int mode = blockIdx.y >> 5;
  const int m0 = (blockIdx.y & 31) * 128, n0 = blockIdx.x * 128;
  const int srow = tid >> 1, shalf = (tid & 1) * 16;
  const int lr = lane & 15, lg = lane >> 4;

  const float* Af = args.A[mode];
  const unsigned short* Wb = args.W[mode];
  const float* bias = args.bias[mode];
  unsigned short* Out = args.out[mode];

  f32x4 acc[4][4] = {};
  f32x4 areg[4];
  u32x4 wreg[2];

  auto gload = [&](int kt) {
    const int k0 = kt * 32;
    const float* s = Af + (size_t)(m0 + srow) * 1024 + k0 + shalf;
    areg[0] = *(const f32x4*)(s);
    areg[1] = *(const f32x4*)(s + 4);
    areg[2] = *(const f32x4*)(s + 8);
    areg[3] = *(const f32x4*)(s + 12);
    const unsigned int* wsrc = (const unsigned int*)(Wb + (size_t)(n0 + srow) * 1024 + k0 + shalf);
    wreg[0] = *(const u32x4*)(wsrc);
    wreg[1] = *(const u32x4*)(wsrc + 4);
  };

  auto swrite = [&](int buf) {
    union { unsigned short us[16]; u32x4 u[2]; } t;
    #pragma unroll
    for (int i = 0; i < 4; ++i) {
      t.us[i*4+0] = f2bf(areg[i][0]); t.us[i*4+1] = f2bf(areg[i][1]);
      t.us[i*4+2] = f2bf(areg[i][2]); t.us[i*4+3] = f2bf(areg[i][3]);
    }
    *(u32x4*)&Al[buf][srow * LDA + shalf]     = t.u[0];
    *(u32x4*)&Al[buf][srow * LDA + shalf + 8] = t.u[1];
    *(u32x4*)&Bl[buf][srow * LDA + shalf]     = wreg[0];
    *(u32x4*)&Bl[buf][srow * LDA + shalf + 8] = wreg[1];
  };

  gload(0);
  swrite(0);
  __syncthreads();

  for (int kt = 0; kt < 32; ++kt) {
    const int buf = kt & 1;
    if (kt < 31) gload(kt + 1);
    bf16x8 af[4], bfr[4];
    #pragma unroll
    for (int mi = 0; mi < 4; ++mi)
      af[mi] = *(const bf16x8*)&Al[buf][(wr * 64 + mi * 16 + lr) * LDA + lg * 8];
    #pragma unroll
    for (int ni = 0; ni < 4; ++ni)
      bfr[ni] = *(const bf16x8*)&Bl[buf][(wc * 64 + ni * 16 + lr) * LDA + lg * 8];
    #pragma unroll
    for (int mi = 0; mi < 4; ++mi)
      #pragma unroll
      for (int ni = 0; ni < 4; ++ni)
        acc[mi][ni] = __builtin_amdgcn_mfma_f32_16x16x32_bf16(af[mi], bfr[ni], acc[mi][ni], 0, 0, 0);
    if (kt < 31) swrite(buf ^ 1);
    __syncthreads();
  }

  float bv[4];
  const int cn = n0 + wc * 64 + lr;
  #pragma unroll
  for (int ni = 0; ni < 4; ++ni) bv[ni] = bias[cn + ni * 16];

  #pragma unroll
  for (int mi = 0; mi < 4; ++mi) {
    #pragma unroll
    for (int j = 0; j < 4; ++j) {
      const int m = m0 + wr * 64 + mi * 16 + lg * 4 + j;
      const int b = m >> 11, l = m & 2047;
      #pragma unroll
      for (int ni = 0; ni < 4; ++ni) {
        const int n = cn + ni * 16;
        const int h = n >> 6, d = n & 63;
        float val = acc[mi][ni][j] + bv[ni];
        if (mode == 0) val *= CQ;
        if (mode == 2)
          Out[((size_t)(b * NH + h) * HD + d) * LL + l] = f2bf(val);
        else
          Out[((size_t)(b * NH + h) * LL + l) * HD + d] = f2bf(val);
      }
    }
  }
}

// ---------------- output GEMM: d_out = ctx Wo^T + bo (A bf16, out fp32) --------
__global__ __launch_bounds__(256, 2) void gemm_out(const unsigned short* __restrict__ Ab,
                                                   const unsigned short* __restrict__ Wb,
                                                   const float* __restrict__ bias,
                                                   float* __restrict__ Out) {
  constexpr int LDA = 40;
  __shared__ alignas(16) unsigned short Al[2][128 * LDA];
  __shared__ alignas(16) unsigned short Bl[2][128 * LDA];

  const int tid = threadIdx.x;
  const int lane = tid & 63;
  const int wave = tid >> 6;
  const int wr = wave >> 1, wc = wave & 1;
  const int m0 = blockIdx.y * 128, n0 = blockIdx.x * 128;
  const int srow = tid >> 1, shalf = (tid & 1) * 16;
  const int lr = lane & 15, lg = lane >> 4;

  f32x4 acc[4][4] = {};
  u32x4 abreg[2], wreg[2];

  auto gload = [&](int kt) {
    const int k0 = kt * 32;
    const unsigned int* s = (const unsigned int*)(Ab + (size_t)(m0 + srow) * 1024 + k0 + shalf);
    abreg[0] = *(const u32x4*)(s);
    abreg[1] = *(const u32x4*)(s + 4);
    const unsigned int* wsrc = (const unsigned int*)(Wb + (size_t)(n0 + srow) * 1024 + k0 + shalf);
    wreg[0] = *(const u32x4*)(wsrc);
    wreg[1] = *(const u32x4*)(wsrc + 4);
  };

  auto swrite = [&](int buf) {
    *(u32x4*)&Al[buf][srow * LDA + shalf]     = abreg[0];
    *(u32x4*)&Al[buf][srow * LDA + shalf + 8] = abreg[1];
    *(u32x4*)&Bl[buf][srow * LDA + shalf]     = wreg[0];
    *(u32x4*)&Bl[buf][srow * LDA + shalf + 8] = wreg[1];
  };

  gload(0);
  swrite(0);
  __syncthreads();

  for (int kt = 0; kt < 32; ++kt) {
    const int buf = kt & 1;
    if (kt < 31) gload(kt + 1);
    bf16x8 af[4], bfr[4];
    #pragma unroll
    for (int mi = 0; mi < 4; ++mi)
      af[mi] = *(const bf16x8*)&Al[buf][(wr * 64 + mi * 16 + lr) * LDA + lg * 8];
    #pragma unroll
    for (int ni = 0; ni < 4; ++ni)
      bfr[ni] = *(const bf16x8*)&Bl[buf][(wc * 64 + ni * 16 + lr) * LDA + lg * 8];
    #pragma unroll
    for (int mi = 0; mi < 4; ++mi)
      #pragma unroll
      for (int ni = 0; ni < 4; ++ni)
        acc[mi][ni] = __builtin_amdgcn_mfma_f32_16x16x32_bf16(af[mi], bfr[ni], acc[mi][ni], 0, 0, 0);
    if (kt < 31) swrite(buf ^ 1);
    __syncthreads();
  }

  float bv[4];
  const int cn = n0 + wc * 64 + lr;
  #pragma unroll
  for (int ni = 0; ni < 4; ++ni) bv[ni] = bias[cn + ni * 16];

  #pragma unroll
  for (int mi = 0; mi < 4; ++mi)
    #pragma unroll
    for (int j = 0; j < 4; ++j) {
      const int m = m0 + wr * 64 + mi * 16 + lg * 4 + j;
      #pragma unroll
      for (int ni = 0; ni < 4; ++ni)
        Out[(size_t)m * 1024 + cn + ni * 16] = acc[mi][ni][j] + bv[ni];
    }
}

// ---------------- flash attention: swapped-QK 32x32, in-register softmax -------
// grid: x = L/128, y = B*H. 4 waves x 32 q-rows. KVB=64 double-buffered LDS.
// S^T = mfma(K, Q): lane owns q = lane&31; kv rows (r&3)+8*(r>>2)+4*hi per tile.
__global__ __launch_bounds__(256, 2) void attn_kernel(const unsigned short* __restrict__ Qh,
                                                      const unsigned short* __restrict__ Kh,
                                                      const unsigned short* __restrict__ Vt,
                                                      unsigned short* __restrict__ Ctx) {
  constexpr int KB = 64;
  constexpr int NT = LL / KB;  // 32
  __shared__ alignas(16) unsigned short Kl[2][KB * HD];   // [kv][d], XOR-swizzled
  __shared__ alignas(16) unsigned short Vl[2][HD * KB];   // [d][kv], XOR-swizzled

  const int tid = threadIdx.x;
  const int lane = tid & 63;
  const int wave = tid >> 6;
  const int lq = lane & 31;
  const int hi = lane >> 5;
  const int bh = blockIdx.y;
  const int q0 = blockIdx.x * 128 + wave * 32;

  const unsigned short* Kg = Kh + (size_t)bh * LL * HD;
  const unsigned short* Vg = Vt + (size_t)bh * HD * LL;

  // Q B-fragments: col=q (lane&31), k = hi*8+e within each 16-d slice
  bf16x8 qf[4];
  {
    const unsigned short* qp = Qh + (size_t)bh * LL * HD + (size_t)(q0 + lq) * HD + hi * 8;
    #pragma unroll
    for (int s = 0; s < 4; ++s) qf[s] = *(const bf16x8*)(qp + s * 16);
  }

  f32x16 oacc0 = {}, oacc1 = {};   // O^T: d rows 0..31 / 32..63, col = q
  float m_ = -1e30f, s_ = 0.f;     // per-lane (per-q) running stats, exp2 domain

  auto stage = [&](int buf, int t) {
    #pragma unroll
    for (int shot = 0; shot < 2; ++shot) {
      const int o = shot * 4096 + tid * 16;
      const int row = o >> 7, col = o & 127;
      const int sc = col ^ ((row & 7) << 4);           // pre-swizzled source (T2)
      gload_lds16((const char*)Kg + (size_t)(t * KB + row) * (HD * 2) + sc,
                  (char*)&Kl[buf][0] + o);
    }
    #pragma unroll
    for (int shot = 0; shot < 2; ++shot) {
      const int o = shot * 4096 + tid * 16;
      const int row = o >> 7, col = o & 127;
      const int sc = col ^ ((row & 7) << 4);
      gload_lds16((const char*)Vg + (size_t)row * (LL * 2) + t * (KB * 2) + sc,
                  (char*)&Vl[buf][0] + o);
    }
  };

  stage(0, 0);
  __syncthreads();

  for (int t = 0; t < NT; ++t) {
    const int buf = t & 1;
    if (t + 1 < NT) stage(buf ^ 1, t + 1);   // prefetch; drained at the barrier

    // ---- S^T = K . Q : two 32x32 tiles over kv
    f32x16 st0 = {}, st1 = {};
    const int swz = (lq & 7) << 4;
    __builtin_amdgcn_s_setprio(1);
    #pragma unroll
    for (int s = 0; s < 4; ++s) {
      const int off = ((s * 32 + hi * 16) ^ swz);
      bf16x8 k0 = *(const bf16x8*)((const char*)&Kl[buf][0] + lq * 128 + off);
      bf16x8 k1 = *(const bf16x8*)((const char*)&Kl[buf][0] + (32 + lq) * 128 + off);
      st0 = __builtin_amdgcn_mfma_f32_32x32x16_bf16(k0, qf[s], st0, 0, 0, 0);
      st1 = __builtin_amdgcn_mfma_f32_32x32x16_bf16(k1, qf[s], st1, 0, 0, 0);
    }
    __builtin_amdgcn_s_setprio(0);

    // ---- in-register row max (32 vals/lane) + cross-half combine
    float tv[8];
    #pragma unroll
    for (int i = 0; i < 8; ++i)
      tv[i] = fmaxf(fmaxf(st0[i], st0[i + 8]), fmaxf(st1[i], st1[i + 8]));
    float pmax = fmaxf(fmaxf(fmaxf(tv[0], tv[1]), fmaxf(tv[2], tv[3])),
                       fmaxf(fmaxf(tv[4], tv[5]), fmaxf(tv[6], tv[7])));
    pmax = fmaxf(pmax, __shfl_xor(pmax, 32));

    // ---- defer-max rescale (T13, THR=8 in log2 units)
    if (!__all(pmax - m_ <= 8.f)) {
      const float nm = fmaxf(m_, pmax);
      const float al = exp2v(m_ - nm);
      m_ = nm;
      s_ *= al;
      #pragma unroll
      for (int i = 0; i < 16; ++i) { oacc0[i] *= al; oacc1[i] *= al; }
    }

    // ---- P = exp2(S' - m) in place + lane-local partial sum
    float a4[4] = {0.f, 0.f, 0.f, 0.f};
    #pragma unroll
    for (int i = 0; i < 16; ++i) {
      float y0 = exp2v(st0[i] - m_);
      float y1 = exp2v(st1[i] - m_);
      st0[i] = y0; st1[i] = y1;
      a4[i & 3] += y0; a4[i & 3] += y1;
    }
    s_ += (a4[0] + a4[1]) + (a4[2] + a4[3]);

    // ---- build P^T B-fragments: 4 slices of 16 kv (cvt_pk + cross-half shfl)
    bf16x8 pfr[4];
    #pragma unroll
    for (int s = 0; s < 4; ++s) {
      const int r = (s & 1) * 8;
      float p0, p1, p2, p3, p4, p5, p6, p7;
      if (s < 2) {
        p0 = st0[r+0]; p1 = st0[r+1]; p2 = st0[r+2]; p3 = st0[r+3];
        p4 = st0[r+4]; p5 = st0[r+5]; p6 = st0[r+6]; p7 = st0[r+7];
      } else {
        p0 = st1[r+0]; p1 = st1[r+1]; p2 = st1[r+2]; p3 = st1[r+3];
        p4 = st1[r+4]; p5 = st1[r+5]; p6 = st1[r+6]; p7 = st1[r+7];
      }
      const unsigned A0 = cvtpk(p0, p1);  // kv pair (0,1)+4hi within slice
      const unsigned A1 = cvtpk(p2, p3);  // (2,3)+4hi
      const unsigned A2 = cvtpk(p4, p5);  // (8,9)+4hi
      const unsigned A3 = cvtpk(p6, p7);  // (10,11)+4hi
      const unsigned t0 = (unsigned)__shfl_xor((int)A0, 32);
      const unsigned t1 = (unsigned)__shfl_xor((int)A1, 32);
      const unsigned t2 = (unsigned)__shfl_xor((int)A2, 32);
      const unsigned t3 = (unsigned)__shfl_xor((int)A3, 32);
      union { unsigned u[4]; bf16x8 v; } pf;
      pf.u[0] = hi ? t2 : A0;   // k = hi*8 + (0,1)
      pf.u[1] = hi ? t3 : A1;   // k = hi*8 + (2,3)
      pf.u[2] = hi ? A2 : t0;   // k = hi*8 + (4,5)
      pf.u[3] = hi ? A3 : t1;   // k = hi*8 + (6,7)
      pfr[s] = pf.v;
    }

    // ---- O^T += V^T . P^T
    __builtin_amdgcn_s_setprio(1);
    #pragma unroll
    for (int s = 0; s < 4; ++s) {
      const int off = ((s * 32 + hi * 16) ^ swz);
      bf16x8 v0 = *(const bf16x8*)((const char*)&Vl[buf][0] + lq * 128 + off);
      bf16x8 v1 = *(const bf16x8*)((const char*)&Vl[buf][0] + (32 + lq) * 128 + off);
      oacc0 = __builtin_amdgcn_mfma_f32_32x32x16_bf16(v0, pfr[s], oacc0, 0, 0, 0);
      oacc1 = __builtin_amdgcn_mfma_f32_32x32x16_bf16(v1, pfr[s], oacc1, 0, 0, 0);
    }
    __builtin_amdgcn_s_setprio(0);
    __syncthreads();
  }

  // ---- finalize: combine halves of the denominator, normalize, write ctx
  s_ += __shfl_xor(s_, 32);
  const float inv = 1.0f / s_;
  const int b = bh >> 4, h = bh & 15;
  const int q = q0 + lq;
  unsigned short* op = Ctx + ((size_t)(b * LL + q)) * MD + h * HD;
  #pragma unroll
  for (int g = 0; g < 4; ++g) {
    {
      union { unsigned short us[4]; u32x2 u; } w;
      #pragma unroll
      for (int j = 0; j < 4; ++j) w.us[j] = f2bf(oacc0[g * 4 + j] * inv);
      *(u32x2*)(op + 8 * g + 4 * hi) = w.u;          // d = 8g+4hi+j
    }
    {
      union { unsigned short us[4]; u32x2 u; } w;
      #pragma unroll
      for (int j = 0; j < 4; ++j) w.us[j] = f2bf(oacc1[g * 4 + j] * inv);
      *(u32x2*)(op + 32 + 8 * g + 4 * hi) = w.u;     // d = 32+8g+4hi+j
    }
  }
}

extern "C" void kernel_launch(void* const* d_in, const int* in_sizes, int n_in,
                              void* d_out, int out_size, void* d_ws, size_t ws_size,
                              hipStream_t stream) {
  const float* q  = (const float*)d_in[0];
  const float* k  = (const float*)d_in[1];
  const float* v  = (const float*)d_in[2];
  const float* Wq = (const float*)d_in[3];
  const float* bq = (const float*)d_in[4];
  const float* Wk = (const float*)d_in[5];
  const float* bk = (const float*)d_in[6];
  const float* Wv = (const float*)d_in[7];
  const float* bv = (const float*)d_in[8];
  const float* Wo = (const float*)d_in[9];
  const float* bo = (const float*)d_in[10];

  char* ws = (char*)d_ws;
  const size_t MB = 1u << 20;
  unsigned short* Wqb = (unsigned short*)(ws + 0 * MB);
  unsigned short* Wkb = (unsigned short*)(ws + 2 * MB);
  unsigned short* Wvb = (unsigned short*)(ws + 4 * MB);
  unsigned short* Wob = (unsigned short*)(ws + 6 * MB);
  unsigned short* Qhb = (unsigned short*)(ws + 8 * MB);
  unsigned short* Khb = (unsigned short*)(ws + 16 * MB);
  unsigned short* Vtb = (unsigned short*)(ws + 24 * MB);
  unsigned short* ctx = (unsigned short*)(ws + 32 * MB);

  cvt_w_kernel<<<512, 256, 0, stream>>>(Wq, Wqb);
  cvt_w_kernel<<<512, 256, 0, stream>>>(Wk, Wkb);
  cvt_w_kernel<<<512, 256, 0, stream>>>(Wv, Wvb);
  cvt_w_kernel<<<512, 256, 0, stream>>>(Wo, Wob);

  QKVArgs args;
  args.A[0] = q;  args.A[1] = k;  args.A[2] = v;
  args.W[0] = Wqb; args.W[1] = Wkb; args.W[2] = Wvb;
  args.bias[0] = bq; args.bias[1] = bk; args.bias[2] = bv;
  args.out[0] = Qhb; args.out[1] = Khb; args.out[2] = Vtb;
  gemm_qkv<<<dim3(8, 96), 256, 0, stream>>>(args);

  attn_kernel<<<dim3(16, 32), 256, 0, stream>>>(Qhb, Khb, Vtb, ctx);

  gemm_out<<<dim3(8, 32), 256, 0, stream>>>(ctx, Wob, bo, (float*)d_out);
}

// Round 3
// 152.069 us; speedup vs baseline: 1.6937x; 1.1531x over previous
//
#include <hip/hip_runtime.h>

// MHA: out = softmax((xWq^T+bq)(xWk^T+bk)^T / sqrt(64)) (xWv^T+bv) Wo^T + bo
// B=2, L=2048, D=1024, H=16, Hd=64. bf16 MFMA pipeline, fp32 accum.
// R3: XCD-aware block swizzle (T1), global_load_lds W-staging with
// source-swizzled linear LDS (T2/rule21), cvt_pk staging conversion.

typedef __attribute__((ext_vector_type(4))) float f32x4;
typedef __attribute__((ext_vector_type(16))) float f32x16;
typedef __attribute__((ext_vector_type(4))) unsigned int u32x4;
typedef __attribute__((ext_vector_type(2))) unsigned int u32x2;
typedef __attribute__((ext_vector_type(8))) short bf16x8;

#define DEVI static __device__ __forceinline__

DEVI unsigned short f2bf(float x) {  // round-to-nearest-even fp32 -> bf16
  union { float f; unsigned u; } v; v.f = x;
  unsigned r = v.u + 0x7fffu + ((v.u >> 16) & 1u);
  return (unsigned short)(r >> 16);
}

DEVI unsigned cvtpk(float lo, float hi) {  // packed fp32x2 -> bf16x2 (RNE)
  unsigned r;
  asm("v_cvt_pk_bf16_f32 %0, %1, %2" : "=v"(r) : "v"(lo), "v"(hi));
  return r;
}

DEVI float exp2v(float x) {  // 2^x via v_exp_f32
  float y;
  asm("v_exp_f32 %0, %1" : "=v"(y) : "v"(x));
  return y;
}

DEVI void gload_lds16(const void* g, void* l) {
  __builtin_amdgcn_global_load_lds((__attribute__((address_space(1))) void*)g,
                                   (__attribute__((address_space(3))) void*)l, 16, 0, 0);
}

constexpr int MD = 1024;
constexpr int NH = 16;
constexpr int HD = 64;
constexpr int LL = 2048;
// fold 1/sqrt(64) * log2(e) into Q so softmax runs in exp2 domain
constexpr float CQ = 0.18033688011112042f;

// ---------------- fused fp32 -> bf16 weight convert (4 x 1M elems) -------------
struct Cvt4Args { const float* src[4]; unsigned short* dst[4]; };

__global__ void cvt4_kernel(Cvt4Args a) {
  const int which = blockIdx.x >> 9;              // 512 blocks per matrix
  const int i = ((blockIdx.x & 511) * 256 + threadIdx.x) * 8;
  const float* w = a.src[which];
  unsigned short* o = a.dst[which];
  f32x4 x = *(const f32x4*)(w + i);
  f32x4 y = *(const f32x4*)(w + i + 4);
  union { unsigned u[4]; u32x4 q; } r;
  r.u[0] = cvtpk(x[0], x[1]); r.u[1] = cvtpk(x[2], x[3]);
  r.u[2] = cvtpk(y[0], y[1]); r.u[3] = cvtpk(y[2], y[3]);
  *(u32x4*)(o + i) = r.q;
}

// ---------------- fused QKV GEMM: C = A W^T + b --------------------------------
// mode 0: Q -> Qh[b][h][l][d], scaled by CQ
// mode 1: K -> Kh[b][h][l][d]
// mode 2: V -> Vt[b][h][d][l]  (transposed for attention PV)
struct QKVArgs {
  const float* A[3];
  const unsigned short* W[3];
  const float* bias[3];
  unsigned short* out[3];
};

__global__ __launch_bounds__(256, 2) void gemm_qkv(QKVArgs args) {
  constexpr int LDA = 40;  // padded stride for reg-staged A (2-way = free)
  __shared__ alignas(16) unsigned short Al[2][128 * LDA];
  __shared__ alignas(16) unsigned short Bl[2][128 * 32];   // linear, gload_lds

  const int tid = threadIdx.x;
  const int lane = tid & 63;
  const int wave = tid >> 6;
  const int wr = wave >> 1, wc = wave & 1;
  const int lr = lane & 15, lg = lane >> 4;

  // XCD-aware swizzle: 768 blocks = 8 XCDs x 96; x (n) fastest within a chunk
  const int logical = (int)(blockIdx.x & 7) * 96 + (int)(blockIdx.x >> 3);
  const int n0 = (logical & 7) * 128;
  const int y = logical >> 3;          // 0..95
  const int mode = y >> 5;
  const int m0 = (y & 31) * 128;

  const float* Af = args.A[mode];
  const unsigned short* Wb = args.W[mode];
  const float* bias = args.bias[mode];
  unsigned short* Out = args.out[mode];

  const int srow = tid >> 1, shalf = (tid & 1) * 16;   // A reg-stage mapping
  const int wrow = tid >> 2, wslot = tid & 3;          // W DMA mapping

  f32x4 acc[4][4] = {};
  f32x4 areg[4];

  auto gloadA = [&](int kt) {
    const float* s = Af + (size_t)(m0 + srow) * 1024 + kt * 32 + shalf;
    areg[0] = *(const f32x4*)(s);
    areg[1] = *(const f32x4*)(s + 4);
    areg[2] = *(const f32x4*)(s + 8);
    areg[3] = *(const f32x4*)(s + 12);
  };

  auto stageW = [&](int buf, int kt) {
    const int k0 = kt * 32;
    #pragma unroll
    for (int shot = 0; shot < 2; ++shot) {
      const int row = shot * 64 + wrow;
      const int ss = wslot ^ ((row >> 1) & 3);     // pre-swizzled source (rule 21)
      gload_lds16((const char*)(Wb + (size_t)(n0 + row) * 1024 + k0) + ss * 16,
                  (char*)&Bl[buf][0] + shot * 4096 + wave * 1024);
    }
  };

  auto swriteA = [&](int buf) {
    union { unsigned u[8]; u32x4 q[2]; } t;
    #pragma unroll
    for (int i = 0; i < 4; ++i) {
      t.u[i * 2]     = cvtpk(areg[i][0], areg[i][1]);
      t.u[i * 2 + 1] = cvtpk(areg[i][2], areg[i][3]);
    }
    *(u32x4*)&Al[buf][srow * LDA + shalf]     = t.q[0];
    *(u32x4*)&Al[buf][srow * LDA + shalf + 8] = t.q[1];
  };

  gloadA(0);
  stageW(0, 0);
  swriteA(0);
  __syncthreads();

  for (int kt = 0; kt < 32; ++kt) {
    const int buf = kt & 1;
    if (kt < 31) { gloadA(kt + 1); stageW(buf ^ 1, kt + 1); }
    bf16x8 af[4], bfr[4];
    #pragma unroll
    for (int mi = 0; mi < 4; ++mi)
      af[mi] = *(const bf16x8*)&Al[buf][(wr * 64 + mi * 16 + lr) * LDA + lg * 8];
    #pragma unroll
    for (int ni = 0; ni < 4; ++ni) {
      const int row = wc * 64 + ni * 16 + lr;
      bfr[ni] = *(const bf16x8*)((const char*)&Bl[buf][0] + row * 64 +
                                 (((unsigned)lg ^ ((row >> 1) & 3)) << 4));
    }
    __builtin_amdgcn_s_setprio(1);
    #pragma unroll
    for (int mi = 0; mi < 4; ++mi)
      #pragma unroll
      for (int ni = 0; ni < 4; ++ni)
        acc[mi][ni] = __builtin_amdgcn_mfma_f32_16x16x32_bf16(af[mi], bfr[ni], acc[mi][ni], 0, 0, 0);
    __builtin_amdgcn_s_setprio(0);
    if (kt < 31) swriteA(buf ^ 1);
    __syncthreads();
  }

  float bv[4];
  const int cn = n0 + wc * 64 + lr;
  #pragma unroll
  for (int ni = 0; ni < 4; ++ni) bv[ni] = bias[cn + ni * 16];

  #pragma unroll
  for (int mi = 0; mi < 4; ++mi) {
    #pragma unroll
    for (int j = 0; j < 4; ++j) {
      const int m = m0 + wr * 64 + mi * 16 + lg * 4 + j;
      const int b = m >> 11, l = m & 2047;
      #pragma unroll
      for (int ni = 0; ni < 4; ++ni) {
        const int n = cn + ni * 16;
        const int h = n >> 6, d = n & 63;
        float val = acc[mi][ni][j] + bv[ni];
        if (mode == 0) val *= CQ;
        if (mode == 2)
          Out[((size_t)(b * NH + h) * HD + d) * LL + l] = f2bf(val);
        else
          Out[((size_t)(b * NH + h) * LL + l) * HD + d] = f2bf(val);
      }
    }
  }
}

// ---------------- output GEMM: d_out = ctx Wo^T + bo (A bf16, out fp32) --------
__global__ __launch_bounds__(256, 2) void gemm_out(const unsigned short* __restrict__ Ab,
                                                   const unsigned short* __restrict__ Wb,
                                                   const float* __restrict__ bias,
                                                   float* __restrict__ Out) {
  __shared__ alignas(16) unsigned short Al[2][128 * 32];
  __shared__ alignas(16) unsigned short Bl[2][128 * 32];

  const int tid = threadIdx.x;
  const int lane = tid & 63;
  const int wave = tid >> 6;
  const int wr = wave >> 1, wc = wave & 1;
  const int lr = lane & 15, lg = lane >> 4;

  // XCD swizzle: 256 blocks = 8 x 32
  const int logical = (int)(blockIdx.x & 7) * 32 + (int)(blockIdx.x >> 3);
  const int n0 = (logical & 7) * 128;
  const int m0 = (logical >> 3) * 128;

  const int wrow = tid >> 2, wslot = tid & 3;

  f32x4 acc[4][4] = {};

  auto stage = [&](int buf, int kt, const unsigned short* src, unsigned short* dstbase) {
    const int k0 = kt * 32;
    #pragma unroll
    for (int shot = 0; shot < 2; ++shot) {
      const int row = shot * 64 + wrow;
      const int ss = wslot ^ ((row >> 1) & 3);
      gload_lds16((const char*)(src + (size_t)row * 1024 + k0) + ss * 16,
                  (char*)dstbase + shot * 4096 + wave * 1024);
    }
  };

  stage(0, 0, Ab + (size_t)m0 * 1024, &Al[0][0]);
  stage(0, 0, Wb + (size_t)n0 * 1024, &Bl[0][0]);
  __syncthreads();

  for (int kt = 0; kt < 32; ++kt) {
    const int buf = kt & 1;
    if (kt < 31) {
      stage(buf ^ 1, kt + 1, Ab + (size_t)m0 * 1024, &Al[buf ^ 1][0]);
      stage(buf ^ 1, kt + 1, Wb + (size_t)n0 * 1024, &Bl[buf ^ 1][0]);
    }
    bf16x8 af[4], bfr[4];
    #pragma unroll
    for (int mi = 0; mi < 4; ++mi) {
      const int row = wr * 64 + mi * 16 + lr;
      af[mi] = *(const bf16x8*)((const char*)&Al[buf][0] + row * 64 +
                                (((unsigned)lg ^ ((row >> 1) & 3)) << 4));
    }
    #pragma unroll
    for (int ni = 0; ni < 4; ++ni) {
      const int row = wc * 64 + ni * 16 + lr;
      bfr[ni] = *(const bf16x8*)((const char*)&Bl[buf][0] + row * 64 +
                                 (((unsigned)lg ^ ((row >> 1) & 3)) << 4));
    }
    __builtin_amdgcn_s_setprio(1);
    #pragma unroll
    for (int mi = 0; mi < 4; ++mi)
      #pragma unroll
      for (int ni = 0; ni < 4; ++ni)
        acc[mi][ni] = __builtin_amdgcn_mfma_f32_16x16x32_bf16(af[mi], bfr[ni], acc[mi][ni], 0, 0, 0);
    __builtin_amdgcn_s_setprio(0);
    __syncthreads();
  }

  float bv[4];
  const int cn = n0 + wc * 64 + lr;
  #pragma unroll
  for (int ni = 0; ni < 4; ++ni) bv[ni] = bias[cn + ni * 16];

  #pragma unroll
  for (int mi = 0; mi < 4; ++mi)
    #pragma unroll
    for (int j = 0; j < 4; ++j) {
      const int m = m0 + wr * 64 + mi * 16 + lg * 4 + j;
      #pragma unroll
      for (int ni = 0; ni < 4; ++ni)
        Out[(size_t)m * 1024 + cn + ni * 16] = acc[mi][ni][j] + bv[ni];
    }
}

// ---------------- flash attention: swapped-QK 32x32, in-register softmax -------
// 512 blocks (XCD-swizzled). 4 waves x 32 q-rows. KB=64 double-buffered LDS.
__global__ __launch_bounds__(256, 2) void attn_kernel(const unsigned short* __restrict__ Qh,
                                                      const unsigned short* __restrict__ Kh,
                                                      const unsigned short* __restrict__ Vt,
                                                      unsigned short* __restrict__ Ctx) {
  constexpr int KB = 64;
  constexpr int NT = LL / KB;  // 32
  __shared__ alignas(16) unsigned short Kl[2][KB * HD];   // [kv][d], XOR-swizzled
  __shared__ alignas(16) unsigned short Vl[2][HD * KB];   // [d][kv], XOR-swizzled

  const int tid = threadIdx.x;
  const int lane = tid & 63;
  const int wave = tid >> 6;
  const int lq = lane & 31;
  const int hi = lane >> 5;

  // XCD swizzle: 512 blocks = 8 x 64; q-block fastest within a chunk
  const int logical = (int)(blockIdx.x & 7) * 64 + (int)(blockIdx.x >> 3);
  const int bh = logical >> 4;
  const int q0 = (logical & 15) * 128 + wave * 32;

  const unsigned short* Kg = Kh + (size_t)bh * LL * HD;
  const unsigned short* Vg = Vt + (size_t)bh * HD * LL;

  bf16x8 qf[4];
  {
    const unsigned short* qp = Qh + (size_t)bh * LL * HD + (size_t)(q0 + lq) * HD + hi * 8;
    #pragma unroll
    for (int s = 0; s < 4; ++s) qf[s] = *(const bf16x8*)(qp + s * 16);
  }

  f32x16 oacc0 = {}, oacc1 = {};   // O^T: d rows 0..31 / 32..63, col = q
  float m_ = -1e30f, s_ = 0.f;     // per-lane (per-q) stats, exp2 domain

  auto stage = [&](int buf, int t) {
    #pragma unroll
    for (int shot = 0; shot < 2; ++shot) {
      const int o = shot * 4096 + tid * 16;
      const int row = o >> 7, col = o & 127;
      const int sc = col ^ ((row & 7) << 4);           // pre-swizzled source (T2)
      gload_lds16((const char*)Kg + (size_t)(t * KB + row) * (HD * 2) + sc,
                  (char*)&Kl[buf][0] + shot * 4096 + wave * 1024);
    }
    #pragma unroll
    for (int shot = 0; shot < 2; ++shot) {
      const int o = shot * 4096 + tid * 16;
      const int row = o >> 7, col = o & 127;
      const int sc = col ^ ((row & 7) << 4);
      gload_lds16((const char*)Vg + (size_t)row * (LL * 2) + t * (KB * 2) + sc,
                  (char*)&Vl[buf][0] + shot * 4096 + wave * 1024);
    }
  };

  stage(0, 0);
  __syncthreads();

  for (int t = 0; t < NT; ++t) {
    const int buf = t & 1;
    if (t + 1 < NT) stage(buf ^ 1, t + 1);   // prefetch; drained at the barrier

    // ---- S^T = K . Q : two 32x32 tiles over kv
    f32x16 st0 = {}, st1 = {};
    const int swz = (lq & 7) << 4;
    __builtin_amdgcn_s_setprio(1);
    #pragma unroll
    for (int s = 0; s < 4; ++s) {
      const int off = ((s * 32 + hi * 16) ^ swz);
      bf16x8 k0 = *(const bf16x8*)((const char*)&Kl[buf][0] + lq * 128 + off);
      bf16x8 k1 = *(const bf16x8*)((const char*)&Kl[buf][0] + (32 + lq) * 128 + off);
      st0 = __builtin_amdgcn_mfma_f32_32x32x16_bf16(k0, qf[s], st0, 0, 0, 0);
      st1 = __builtin_amdgcn_mfma_f32_32x32x16_bf16(k1, qf[s], st1, 0, 0, 0);
    }
    __builtin_amdgcn_s_setprio(0);

    // ---- in-register row max + cross-half combine
    float tv[8];
    #pragma unroll
    for (int i = 0; i < 8; ++i)
      tv[i] = fmaxf(fmaxf(st0[i], st0[i + 8]), fmaxf(st1[i], st1[i + 8]));
    float pmax = fmaxf(fmaxf(fmaxf(tv[0], tv[1]), fmaxf(tv[2], tv[3])),
                       fmaxf(fmaxf(tv[4], tv[5]), fmaxf(tv[6], tv[7])));
    pmax = fmaxf(pmax, __shfl_xor(pmax, 32));

    // ---- defer-max rescale (T13, THR=8 in log2 units)
    if (!__all(pmax - m_ <= 8.f)) {
      const float nm = fmaxf(m_, pmax);
      const float al = exp2v(m_ - nm);
      m_ = nm;
      s_ *= al;
      #pragma unroll
      for (int i = 0; i < 16; ++i) { oacc0[i] *= al; oacc1[i] *= al; }
    }

    // ---- P = exp2(S' - m) in place + lane-local partial sum
    float a4[4] = {0.f, 0.f, 0.f, 0.f};
    #pragma unroll
    for (int i = 0; i < 16; ++i) {
      float y0 = exp2v(st0[i] - m_);
      float y1 = exp2v(st1[i] - m_);
      st0[i] = y0; st1[i] = y1;
      a4[i & 3] += y0; a4[i & 3] += y1;
    }
    s_ += (a4[0] + a4[1]) + (a4[2] + a4[3]);

    // ---- build P^T B-fragments (cvt_pk + cross-half shfl)
    bf16x8 pfr[4];
    #pragma unroll
    for (int s = 0; s < 4; ++s) {
      const int r = (s & 1) * 8;
      float p0, p1, p2, p3, p4, p5, p6, p7;
      if (s < 2) {
        p0 = st0[r+0]; p1 = st0[r+1]; p2 = st0[r+2]; p3 = st0[r+3];
        p4 = st0[r+4]; p5 = st0[r+5]; p6 = st0[r+6]; p7 = st0[r+7];
      } else {
        p0 = st1[r+0]; p1 = st1[r+1]; p2 = st1[r+2]; p3 = st1[r+3];
        p4 = st1[r+4]; p5 = st1[r+5]; p6 = st1[r+6]; p7 = st1[r+7];
      }
      const unsigned A0 = cvtpk(p0, p1);
      const unsigned A1 = cvtpk(p2, p3);
      const unsigned A2 = cvtpk(p4, p5);
      const unsigned A3 = cvtpk(p6, p7);
      const unsigned t0 = (unsigned)__shfl_xor((int)A0, 32);
      const unsigned t1 = (unsigned)__shfl_xor((int)A1, 32);
      const unsigned t2 = (unsigned)__shfl_xor((int)A2, 32);
      const unsigned t3 = (unsigned)__shfl_xor((int)A3, 32);
      union { unsigned u[4]; bf16x8 v; } pf;
      pf.u[0] = hi ? t2 : A0;
      pf.u[1] = hi ? t3 : A1;
      pf.u[2] = hi ? A2 : t0;
      pf.u[3] = hi ? A3 : t1;
      pfr[s] = pf.v;
    }

    // ---- O^T += V^T . P^T
    __builtin_amdgcn_s_setprio(1);
    #pragma unroll
    for (int s = 0; s < 4; ++s) {
      const int off = ((s * 32 + hi * 16) ^ swz);
      bf16x8 v0 = *(const bf16x8*)((const char*)&Vl[buf][0] + lq * 128 + off);
      bf16x8 v1 = *(const bf16x8*)((const char*)&Vl[buf][0] + (32 + lq) * 128 + off);
      oacc0 = __builtin_amdgcn_mfma_f32_32x32x16_bf16(v0, pfr[s], oacc0, 0, 0, 0);
      oacc1 = __builtin_amdgcn_mfma_f32_32x32x16_bf16(v1, pfr[s], oacc1, 0, 0, 0);
    }
    __builtin_amdgcn_s_setprio(0);
    __syncthreads();
  }

  // ---- finalize
  s_ += __shfl_xor(s_, 32);
  const float inv = 1.0f / s_;
  const int b = bh >> 4, h = bh & 15;
  const int q = q0 + lq;
  unsigned short* op = Ctx + ((size_t)(b * LL + q)) * MD + h * HD;
  #pragma unroll
  for (int g = 0; g < 4; ++g) {
    {
      union { unsigned short us[4]; u32x2 u; } w;
      #pragma unroll
      for (int j = 0; j < 4; ++j) w.us[j] = f2bf(oacc0[g * 4 + j] * inv);
      *(u32x2*)(op + 8 * g + 4 * hi) = w.u;
    }
    {
      union { unsigned short us[4]; u32x2 u; } w;
      #pragma unroll
      for (int j = 0; j < 4; ++j) w.us[j] = f2bf(oacc1[g * 4 + j] * inv);
      *(u32x2*)(op + 32 + 8 * g + 4 * hi) = w.u;
    }
  }
}

extern "C" void kernel_launch(void* const* d_in, const int* in_sizes, int n_in,
                              void* d_out, int out_size, void* d_ws, size_t ws_size,
                              hipStream_t stream) {
  const float* q  = (const float*)d_in[0];
  const float* k  = (const float*)d_in[1];
  const float* v  = (const float*)d_in[2];
  const float* Wq = (const float*)d_in[3];
  const float* bq = (const float*)d_in[4];
  const float* Wk = (const float*)d_in[5];
  const float* bk = (const float*)d_in[6];
  const float* Wv = (const float*)d_in[7];
  const float* bv = (const float*)d_in[8];
  const float* Wo = (const float*)d_in[9];
  const float* bo = (const float*)d_in[10];

  char* ws = (char*)d_ws;
  const size_t MB = 1u << 20;
  unsigned short* Wqb = (unsigned short*)(ws + 0 * MB);
  unsigned short* Wkb = (unsigned short*)(ws + 2 * MB);
  unsigned short* Wvb = (unsigned short*)(ws + 4 * MB);
  unsigned short* Wob = (unsigned short*)(ws + 6 * MB);
  unsigned short* Qhb = (unsigned short*)(ws + 8 * MB);
  unsigned short* Khb = (unsigned short*)(ws + 16 * MB);
  unsigned short* Vtb = (unsigned short*)(ws + 24 * MB);
  unsigned short* ctx = (unsigned short*)(ws + 32 * MB);

  Cvt4Args ca;
  ca.src[0] = Wq; ca.src[1] = Wk; ca.src[2] = Wv; ca.src[3] = Wo;
  ca.dst[0] = Wqb; ca.dst[1] = Wkb; ca.dst[2] = Wvb; ca.dst[3] = Wob;
  cvt4_kernel<<<2048, 256, 0, stream>>>(ca);

  QKVArgs args;
  args.A[0] = q;  args.A[1] = k;  args.A[2] = v;
  args.W[0] = Wqb; args.W[1] = Wkb; args.W[2] = Wvb;
  args.bias[0] = bq; args.bias[1] = bk; args.bias[2] = bv;
  args.out[0] = Qhb; args.out[1] = Khb; args.out[2] = Vtb;
  gemm_qkv<<<768, 256, 0, stream>>>(args);

  attn_kernel<<<512, 256, 0, stream>>>(Qhb, Khb, Vtb, ctx);

  gemm_out<<<256, 256, 0, stream>>>(ctx, Wob, bo, (float*)d_out);
}

// Round 4
// 151.394 us; speedup vs baseline: 1.7012x; 1.0045x over previous
//
#include <hip/hip_runtime.h>

// MHA: out = softmax((xWq^T+bq)(xWk^T+bk)^T / sqrt(64)) (xWv^T+bv) Wo^T + bo
// B=2, L=2048, D=1024, H=16, Hd=64. bf16 MFMA pipeline, fp32 accum.
// R4: counted-vmcnt pipeline (T4) — raw s_barrier + s_waitcnt vmcnt(N), never
// draining to 0 in the main loops. Loads stay in flight across barriers.

typedef __attribute__((ext_vector_type(4))) float f32x4;
typedef __attribute__((ext_vector_type(16))) float f32x16;
typedef __attribute__((ext_vector_type(4))) unsigned int u32x4;
typedef __attribute__((ext_vector_type(2))) unsigned int u32x2;
typedef __attribute__((ext_vector_type(8))) short bf16x8;

#define DEVI static __device__ __forceinline__

DEVI unsigned short f2bf(float x) {  // round-to-nearest-even fp32 -> bf16
  union { float f; unsigned u; } v; v.f = x;
  unsigned r = v.u + 0x7fffu + ((v.u >> 16) & 1u);
  return (unsigned short)(r >> 16);
}

DEVI unsigned cvtpk(float lo, float hi) {  // packed fp32x2 -> bf16x2 (RNE)
  unsigned r;
  asm("v_cvt_pk_bf16_f32 %0, %1, %2" : "=v"(r) : "v"(lo), "v"(hi));
  return r;
}

DEVI float exp2v(float x) {  // 2^x via v_exp_f32
  float y;
  asm("v_exp_f32 %0, %1" : "=v"(y) : "v"(x));
  return y;
}

DEVI void gload_lds16(const void* g, void* l) {
  __builtin_amdgcn_global_load_lds((__attribute__((address_space(1))) void*)g,
                                   (__attribute__((address_space(3))) void*)l, 16, 0, 0);
}

#define WAIT_VM(N) asm volatile("s_waitcnt vmcnt(" #N ")" ::: "memory")
#define WAIT_LGKM0 asm volatile("s_waitcnt lgkmcnt(0)" ::: "memory")
#define BARRIER __builtin_amdgcn_s_barrier()

constexpr int MD = 1024;
constexpr int NH = 16;
constexpr int HD = 64;
constexpr int LL = 2048;
// fold 1/sqrt(64) * log2(e) into Q so softmax runs in exp2 domain
constexpr float CQ = 0.18033688011112042f;

// ---------------- fused fp32 -> bf16 weight convert (4 x 1M elems) -------------
struct Cvt4Args { const float* src[4]; unsigned short* dst[4]; };

__global__ void cvt4_kernel(Cvt4Args a) {
  const int which = blockIdx.x >> 9;              // 512 blocks per matrix
  const int i = ((blockIdx.x & 511) * 256 + threadIdx.x) * 8;
  const float* w = a.src[which];
  unsigned short* o = a.dst[which];
  f32x4 x = *(const f32x4*)(w + i);
  f32x4 y = *(const f32x4*)(w + i + 4);
  union { unsigned u[4]; u32x4 q; } r;
  r.u[0] = cvtpk(x[0], x[1]); r.u[1] = cvtpk(x[2], x[3]);
  r.u[2] = cvtpk(y[0], y[1]); r.u[3] = cvtpk(y[2], y[3]);
  *(u32x4*)(o + i) = r.q;
}

// ---------------- fused QKV GEMM: C = A W^T + b --------------------------------
// mode 0: Q -> Qh[b][h][l][d], scaled by CQ
// mode 1: K -> Kh[b][h][l][d]
// mode 2: V -> Vt[b][h][d][l]  (transposed for attention PV)
struct QKVArgs {
  const float* A[3];
  const unsigned short* W[3];
  const float* bias[3];
  unsigned short* out[3];
};

__global__ __launch_bounds__(256, 2) void gemm_qkv(QKVArgs args) {
  constexpr int LDA = 40;  // padded stride for reg-staged A (2-way = free)
  __shared__ alignas(16) unsigned short Al[2][128 * LDA];
  __shared__ alignas(16) unsigned short Bl[2][128 * 32];   // linear, gload_lds

  const int tid = threadIdx.x;
  const int lane = tid & 63;
  const int wave = tid >> 6;
  const int wr = wave >> 1, wc = wave & 1;
  const int lr = lane & 15, lg = lane >> 4;

  // XCD-aware swizzle: 768 blocks = 8 XCDs x 96; x (n) fastest within a chunk
  const int logical = (int)(blockIdx.x & 7) * 96 + (int)(blockIdx.x >> 3);
  const int n0 = (logical & 7) * 128;
  const int y = logical >> 3;          // 0..95
  const int mode = y >> 5;
  const int m0 = (y & 31) * 128;

  const float* Af = args.A[mode];
  const unsigned short* Wb = args.W[mode];
  const float* bias = args.bias[mode];
  unsigned short* Out = args.out[mode];

  const int srow = tid >> 1, shalf = (tid & 1) * 16;   // A reg-stage mapping
  const int wrow = tid >> 2, wslot = tid & 3;          // W DMA mapping

  f32x4 acc[4][4] = {};
  f32x4 areg[4];

  auto gloadA = [&](int kt) {
    const float* s = Af + (size_t)(m0 + srow) * 1024 + kt * 32 + shalf;
    areg[0] = *(const f32x4*)(s);
    areg[1] = *(const f32x4*)(s + 4);
    areg[2] = *(const f32x4*)(s + 8);
    areg[3] = *(const f32x4*)(s + 12);
  };

  auto stageW = [&](int b, int kt) {
    const int k0 = kt * 32;
    #pragma unroll
    for (int shot = 0; shot < 2; ++shot) {
      const int row = shot * 64 + wrow;
      const int ss = wslot ^ ((row >> 1) & 3);     // pre-swizzled source (rule 21)
      gload_lds16((const char*)(Wb + (size_t)(n0 + row) * 1024 + k0) + ss * 16,
                  (char*)&Bl[b][0] + shot * 4096 + wave * 1024);
    }
  };

  auto swriteA = [&](int b) {
    union { unsigned u[8]; u32x4 q[2]; } t;
    #pragma unroll
    for (int i = 0; i < 4; ++i) {
      t.u[i * 2]     = cvtpk(areg[i][0], areg[i][1]);
      t.u[i * 2 + 1] = cvtpk(areg[i][2], areg[i][3]);
    }
    *(u32x4*)&Al[b][srow * LDA + shalf]     = t.q[0];
    *(u32x4*)&Al[b][srow * LDA + shalf + 8] = t.q[1];
  };

  // prologue: tile 0 fully staged
  gloadA(0);
  stageW(0, 0);
  swriteA(0);          // compiler auto-waits the A regs
  WAIT_LGKM0;

  for (int kt = 0; kt < 32; ++kt) {
    const int buf = kt & 1;
    if (kt < 31) {
      gloadA(kt + 1);          // queue: [W(t)x2, A(t+1)x4]
      stageW(buf ^ 1, kt + 1); // queue: [W(t)x2, A(t+1)x4, W(t+1)x2]
      WAIT_VM(6);              // W(t) landed in LDS; 6 stay in flight
    } else {
      WAIT_VM(0);              // last tile: drain W(31)
    }
    BARRIER;                   // all waves' W(t) staged + prev ds_writes visible

    bf16x8 af[4], bfr[4];
    #pragma unroll
    for (int mi = 0; mi < 4; ++mi)
      af[mi] = *(const bf16x8*)&Al[buf][(wr * 64 + mi * 16 + lr) * LDA + lg * 8];
    #pragma unroll
    for (int ni = 0; ni < 4; ++ni) {
      const int row = wc * 64 + ni * 16 + lr;
      bfr[ni] = *(const bf16x8*)((const char*)&Bl[buf][0] + row * 64 +
                                 (((unsigned)lg ^ ((row >> 1) & 3)) << 4));
    }
    __builtin_amdgcn_s_setprio(1);
    #pragma unroll
    for (int mi = 0; mi < 4; ++mi)
      #pragma unroll
      for (int ni = 0; ni < 4; ++ni)
        acc[mi][ni] = __builtin_amdgcn_mfma_f32_16x16x32_bf16(af[mi], bfr[ni], acc[mi][ni], 0, 0, 0);
    __builtin_amdgcn_s_setprio(0);

    if (kt < 31) swriteA(buf ^ 1);   // auto vmcnt(2): A(t+1) regs ready
    WAIT_LGKM0;                      // ds_writes done before barrier
    BARRIER;                         // buf safe to overwrite next iter
  }

  float bv[4];
  const int cn = n0 + wc * 64 + lr;
  #pragma unroll
  for (int ni = 0; ni < 4; ++ni) bv[ni] = bias[cn + ni * 16];

  #pragma unroll
  for (int mi = 0; mi < 4; ++mi) {
    #pragma unroll
    for (int j = 0; j < 4; ++j) {
      const int m = m0 + wr * 64 + mi * 16 + lg * 4 + j;
      const int b = m >> 11, l = m & 2047;
      #pragma unroll
      for (int ni = 0; ni < 4; ++ni) {
        const int n = cn + ni * 16;
        const int h = n >> 6, d = n & 63;
        float val = acc[mi][ni][j] + bv[ni];
        if (mode == 0) val *= CQ;
        if (mode == 2)
          Out[((size_t)(b * NH + h) * HD + d) * LL + l] = f2bf(val);
        else
          Out[((size_t)(b * NH + h) * LL + l) * HD + d] = f2bf(val);
      }
    }
  }
}

// ---------------- output GEMM: d_out = ctx Wo^T + bo (A bf16, out fp32) --------
__global__ __launch_bounds__(256, 2) void gemm_out(const unsigned short* __restrict__ Ab,
                                                   const unsigned short* __restrict__ Wb,
                                                   const float* __restrict__ bias,
                                                   float* __restrict__ Out) {
  __shared__ alignas(16) unsigned short Al[2][128 * 32];
  __shared__ alignas(16) unsigned short Bl[2][128 * 32];

  const int tid = threadIdx.x;
  const int lane = tid & 63;
  const int wave = tid >> 6;
  const int wr = wave >> 1, wc = wave & 1;
  const int lr = lane & 15, lg = lane >> 4;

  // XCD swizzle: 256 blocks = 8 x 32
  const int logical = (int)(blockIdx.x & 7) * 32 + (int)(blockIdx.x >> 3);
  const int n0 = (logical & 7) * 128;
  const int m0 = (logical >> 3) * 128;

  const int wrow = tid >> 2, wslot = tid & 3;

  f32x4 acc[4][4] = {};

  auto stage = [&](int b, int kt, const unsigned short* src, unsigned short* dstbase) {
    const int k0 = kt * 32;
    #pragma unroll
    for (int shot = 0; shot < 2; ++shot) {
      const int row = shot * 64 + wrow;
      const int ss = wslot ^ ((row >> 1) & 3);
      gload_lds16((const char*)(src + (size_t)row * 1024 + k0) + ss * 16,
                  (char*)dstbase + shot * 4096 + wave * 1024);
    }
  };

  stage(0, 0, Ab + (size_t)m0 * 1024, &Al[0][0]);
  stage(0, 0, Wb + (size_t)n0 * 1024, &Bl[0][0]);

  for (int kt = 0; kt < 32; ++kt) {
    const int buf = kt & 1;
    if (kt < 31) {
      stage(buf ^ 1, kt + 1, Ab + (size_t)m0 * 1024, &Al[buf ^ 1][0]);
      stage(buf ^ 1, kt + 1, Wb + (size_t)n0 * 1024, &Bl[buf ^ 1][0]);
      WAIT_VM(4);              // tile t landed; t+1's 4 ops stay in flight
    } else {
      WAIT_VM(0);
    }
    BARRIER;

    bf16x8 af[4], bfr[4];
    #pragma unroll
    for (int mi = 0; mi < 4; ++mi) {
      const int row = wr * 64 + mi * 16 + lr;
      af[mi] = *(const bf16x8*)((const char*)&Al[buf][0] + row * 64 +
                                (((unsigned)lg ^ ((row >> 1) & 3)) << 4));
    }
    #pragma unroll
    for (int ni = 0; ni < 4; ++ni) {
      const int row = wc * 64 + ni * 16 + lr;
      bfr[ni] = *(const bf16x8*)((const char*)&Bl[buf][0] + row * 64 +
                                 (((unsigned)lg ^ ((row >> 1) & 3)) << 4));
    }
    __builtin_amdgcn_s_setprio(1);
    #pragma unroll
    for (int mi = 0; mi < 4; ++mi)
      #pragma unroll
      for (int ni = 0; ni < 4; ++ni)
        acc[mi][ni] = __builtin_amdgcn_mfma_f32_16x16x32_bf16(af[mi], bfr[ni], acc[mi][ni], 0, 0, 0);
    __builtin_amdgcn_s_setprio(0);
    BARRIER;                   // all reads of buf done before next-iter staging
  }

  float bv[4];
  const int cn = n0 + wc * 64 + lr;
  #pragma unroll
  for (int ni = 0; ni < 4; ++ni) bv[ni] = bias[cn + ni * 16];

  #pragma unroll
  for (int mi = 0; mi < 4; ++mi)
    #pragma unroll
    for (int j = 0; j < 4; ++j) {
      const int m = m0 + wr * 64 + mi * 16 + lg * 4 + j;
      #pragma unroll
      for (int ni = 0; ni < 4; ++ni)
        Out[(size_t)m * 1024 + cn + ni * 16] = acc[mi][ni][j] + bv[ni];
    }
}

// ---------------- flash attention: swapped-QK 32x32, in-register softmax -------
// 512 blocks (XCD-swizzled). 4 waves x 32 q-rows. KB=64 double-buffered LDS.
__global__ __launch_bounds__(256, 2) void attn_kernel(const unsigned short* __restrict__ Qh,
                                                      const unsigned short* __restrict__ Kh,
                                                      const unsigned short* __restrict__ Vt,
                                                      unsigned short* __restrict__ Ctx) {
  constexpr int KB = 64;
  constexpr int NT = LL / KB;  // 32
  __shared__ alignas(16) unsigned short Kl[2][KB * HD];   // [kv][d], XOR-swizzled
  __shared__ alignas(16) unsigned short Vl[2][HD * KB];   // [d][kv], XOR-swizzled

  const int tid = threadIdx.x;
  const int lane = tid & 63;
  const int wave = tid >> 6;
  const int lq = lane & 31;
  const int hi = lane >> 5;

  // XCD swizzle: 512 blocks = 8 x 64; q-block fastest within a chunk
  const int logical = (int)(blockIdx.x & 7) * 64 + (int)(blockIdx.x >> 3);
  const int bh = logical >> 4;
  const int q0 = (logical & 15) * 128 + wave * 32;

  const unsigned short* Kg = Kh + (size_t)bh * LL * HD;
  const unsigned short* Vg = Vt + (size_t)bh * HD * LL;

  bf16x8 qf[4];
  {
    const unsigned short* qp = Qh + (size_t)bh * LL * HD + (size_t)(q0 + lq) * HD + hi * 8;
    #pragma unroll
    for (int s = 0; s < 4; ++s) qf[s] = *(const bf16x8*)(qp + s * 16);
  }

  f32x16 oacc0 = {}, oacc1 = {};   // O^T: d rows 0..31 / 32..63, col = q
  float m_ = -1e30f, s_ = 0.f;     // per-lane (per-q) stats, exp2 domain

  auto stage = [&](int b, int t) {
    #pragma unroll
    for (int shot = 0; shot < 2; ++shot) {
      const int o = shot * 4096 + tid * 16;
      const int row = o >> 7, col = o & 127;
      const int sc = col ^ ((row & 7) << 4);           // pre-swizzled source (T2)
      gload_lds16((const char*)Kg + (size_t)(t * KB + row) * (HD * 2) + sc,
                  (char*)&Kl[b][0] + shot * 4096 + wave * 1024);
    }
    #pragma unroll
    for (int shot = 0; shot < 2; ++shot) {
      const int o = shot * 4096 + tid * 16;
      const int row = o >> 7, col = o & 127;
      const int sc = col ^ ((row & 7) << 4);
      gload_lds16((const char*)Vg + (size_t)row * (LL * 2) + t * (KB * 2) + sc,
                  (char*)&Vl[b][0] + shot * 4096 + wave * 1024);
    }
  };

  stage(0, 0);

  for (int t = 0; t < NT; ++t) {
    const int buf = t & 1;
    if (t + 1 < NT) {
      stage(buf ^ 1, t + 1);   // 4 more in flight
      WAIT_VM(4);              // tile t staged; t+1 rides across the barrier
    } else {
      WAIT_VM(0);
    }
    BARRIER;

    // ---- S^T = K . Q : two 32x32 tiles over kv
    f32x16 st0 = {}, st1 = {};
    const int swz = (lq & 7) << 4;
    __builtin_amdgcn_s_setprio(1);
    #pragma unroll
    for (int s = 0; s < 4; ++s) {
      const int off = ((s * 32 + hi * 16) ^ swz);
      bf16x8 k0 = *(const bf16x8*)((const char*)&Kl[buf][0] + lq * 128 + off);
      bf16x8 k1 = *(const bf16x8*)((const char*)&Kl[buf][0] + (32 + lq) * 128 + off);
      st0 = __builtin_amdgcn_mfma_f32_32x32x16_bf16(k0, qf[s], st0, 0, 0, 0);
      st1 = __builtin_amdgcn_mfma_f32_32x32x16_bf16(k1, qf[s], st1, 0, 0, 0);
    }
    __builtin_amdgcn_s_setprio(0);

    // ---- in-register row max + cross-half combine
    float tv[8];
    #pragma unroll
    for (int i = 0; i < 8; ++i)
      tv[i] = fmaxf(fmaxf(st0[i], st0[i + 8]), fmaxf(st1[i], st1[i + 8]));
    float pmax = fmaxf(fmaxf(fmaxf(tv[0], tv[1]), fmaxf(tv[2], tv[3])),
                       fmaxf(fmaxf(tv[4], tv[5]), fmaxf(tv[6], tv[7])));
    pmax = fmaxf(pmax, __shfl_xor(pmax, 32));

    // ---- defer-max rescale (T13, THR=8 in log2 units)
    if (!__all(pmax - m_ <= 8.f)) {
      const float nm = fmaxf(m_, pmax);
      const float al = exp2v(m_ - nm);
      m_ = nm;
      s_ *= al;
      #pragma unroll
      for (int i = 0; i < 16; ++i) { oacc0[i] *= al; oacc1[i] *= al; }
    }

    // ---- P = exp2(S' - m) in place + lane-local partial sum
    float a4[4] = {0.f, 0.f, 0.f, 0.f};
    #pragma unroll
    for (int i = 0; i < 16; ++i) {
      float y0 = exp2v(st0[i] - m_);
      float y1 = exp2v(st1[i] - m_);
      st0[i] = y0; st1[i] = y1;
      a4[i & 3] += y0; a4[i & 3] += y1;
    }
    s_ += (a4[0] + a4[1]) + (a4[2] + a4[3]);

    // ---- build P^T B-fragments (cvt_pk + cross-half shfl)
    bf16x8 pfr[4];
    #pragma unroll
    for (int s = 0; s < 4; ++s) {
      const int r = (s & 1) * 8;
      float p0, p1, p2, p3, p4, p5, p6, p7;
      if (s < 2) {
        p0 = st0[r+0]; p1 = st0[r+1]; p2 = st0[r+2]; p3 = st0[r+3];
        p4 = st0[r+4]; p5 = st0[r+5]; p6 = st0[r+6]; p7 = st0[r+7];
      } else {
        p0 = st1[r+0]; p1 = st1[r+1]; p2 = st1[r+2]; p3 = st1[r+3];
        p4 = st1[r+4]; p5 = st1[r+5]; p6 = st1[r+6]; p7 = st1[r+7];
      }
      const unsigned A0 = cvtpk(p0, p1);
      const unsigned A1 = cvtpk(p2, p3);
      const unsigned A2 = cvtpk(p4, p5);
      const unsigned A3 = cvtpk(p6, p7);
      const unsigned t0 = (unsigned)__shfl_xor((int)A0, 32);
      const unsigned t1 = (unsigned)__shfl_xor((int)A1, 32);
      const unsigned t2 = (unsigned)__shfl_xor((int)A2, 32);
      const unsigned t3 = (unsigned)__shfl_xor((int)A3, 32);
      union { unsigned u[4]; bf16x8 v; } pf;
      pf.u[0] = hi ? t2 : A0;
      pf.u[1] = hi ? t3 : A1;
      pf.u[2] = hi ? A2 : t0;
      pf.u[3] = hi ? A3 : t1;
      pfr[s] = pf.v;
    }

    // ---- O^T += V^T . P^T
    __builtin_amdgcn_s_setprio(1);
    #pragma unroll
    for (int s = 0; s < 4; ++s) {
      const int off = ((s * 32 + hi * 16) ^ swz);
      bf16x8 v0 = *(const bf16x8*)((const char*)&Vl[buf][0] + lq * 128 + off);
      bf16x8 v1 = *(const bf16x8*)((const char*)&Vl[buf][0] + (32 + lq) * 128 + off);
      oacc0 = __builtin_amdgcn_mfma_f32_32x32x16_bf16(v0, pfr[s], oacc0, 0, 0, 0);
      oacc1 = __builtin_amdgcn_mfma_f32_32x32x16_bf16(v1, pfr[s], oacc1, 0, 0, 0);
    }
    __builtin_amdgcn_s_setprio(0);
    BARRIER;                   // all reads of buf done before next-iter staging
  }

  // ---- finalize
  s_ += __shfl_xor(s_, 32);
  const float inv = 1.0f / s_;
  const int b = bh >> 4, h = bh & 15;
  const int q = q0 + lq;
  unsigned short* op = Ctx + ((size_t)(b * LL + q)) * MD + h * HD;
  #pragma unroll
  for (int g = 0; g < 4; ++g) {
    {
      union { unsigned short us[4]; u32x2 u; } w;
      #pragma unroll
      for (int j = 0; j < 4; ++j) w.us[j] = f2bf(oacc0[g * 4 + j] * inv);
      *(u32x2*)(op + 8 * g + 4 * hi) = w.u;
    }
    {
      union { unsigned short us[4]; u32x2 u; } w;
      #pragma unroll
      for (int j = 0; j < 4; ++j) w.us[j] = f2bf(oacc1[g * 4 + j] * inv);
      *(u32x2*)(op + 32 + 8 * g + 4 * hi) = w.u;
    }
  }
}

extern "C" void kernel_launch(void* const* d_in, const int* in_sizes, int n_in,
                              void* d_out, int out_size, void* d_ws, size_t ws_size,
                              hipStream_t stream) {
  const float* q  = (const float*)d_in[0];
  const float* k  = (const float*)d_in[1];
  const float* v  = (const float*)d_in[2];
  const float* Wq = (const float*)d_in[3];
  const float* bq = (const float*)d_in[4];
  const float* Wk = (const float*)d_in[5];
  const float* bk = (const float*)d_in[6];
  const float* Wv = (const float*)d_in[7];
  const float* bv = (const float*)d_in[8];
  const float* Wo = (const float*)d_in[9];
  const float* bo = (const float*)d_in[10];

  char* ws = (char*)d_ws;
  const size_t MB = 1u << 20;
  unsigned short* Wqb = (unsigned short*)(ws + 0 * MB);
  unsigned short* Wkb = (unsigned short*)(ws + 2 * MB);
  unsigned short* Wvb = (unsigned short*)(ws + 4 * MB);
  unsigned short* Wob = (unsigned short*)(ws + 6 * MB);
  unsigned short* Qhb = (unsigned short*)(ws + 8 * MB);
  unsigned short* Khb = (unsigned short*)(ws + 16 * MB);
  unsigned short* Vtb = (unsigned short*)(ws + 24 * MB);
  unsigned short* ctx = (unsigned short*)(ws + 32 * MB);

  Cvt4Args ca;
  ca.src[0] = Wq; ca.src[1] = Wk; ca.src[2] = Wv; ca.src[3] = Wo;
  ca.dst[0] = Wqb; ca.dst[1] = Wkb; ca.dst[2] = Wvb; ca.dst[3] = Wob;
  cvt4_kernel<<<2048, 256, 0, stream>>>(ca);

  QKVArgs args;
  args.A[0] = q;  args.A[1] = k;  args.A[2] = v;
  args.W[0] = Wqb; args.W[1] = Wkb; args.W[2] = Wvb;
  args.bias[0] = bq; args.bias[1] = bk; args.bias[2] = bv;
  args.out[0] = Qhb; args.out[1] = Khb; args.out[2] = Vtb;
  gemm_qkv<<<768, 256, 0, stream>>>(args);

  attn_kernel<<<512, 256, 0, stream>>>(Qhb, Khb, Vtb, ctx);

  gemm_out<<<256, 256, 0, stream>>>(ctx, Wob, bo, (float*)d_out);
}

// Round 5
// 146.019 us; speedup vs baseline: 1.7639x; 1.0368x over previous
//
#include <hip/hip_runtime.h>

// MHA: out = softmax((xWq^T+bq)(xWk^T+bk)^T / sqrt(64)) (xWv^T+bv) Wo^T + bo
// B=2, L=2048, D=1024, H=16, Hd=64. bf16 MFMA pipeline, fp32 accum.
// R5: gemm_qkv A-path converted from reg-staging (latency-serial, m151) to
// direct fp32 global_load_lds with slot-XOR swizzle; fp32->bf16 happens at
// fragment-read time. Pure-DMA loop, counted vmcnt(6), no ds_writes.

typedef __attribute__((ext_vector_type(4))) float f32x4;
typedef __attribute__((ext_vector_type(16))) float f32x16;
typedef __attribute__((ext_vector_type(4))) unsigned int u32x4;
typedef __attribute__((ext_vector_type(2))) unsigned int u32x2;
typedef __attribute__((ext_vector_type(8))) short bf16x8;

#define DEVI static __device__ __forceinline__

DEVI unsigned short f2bf(float x) {  // round-to-nearest-even fp32 -> bf16
  union { float f; unsigned u; } v; v.f = x;
  unsigned r = v.u + 0x7fffu + ((v.u >> 16) & 1u);
  return (unsigned short)(r >> 16);
}

DEVI unsigned cvtpk(float lo, float hi) {  // packed fp32x2 -> bf16x2 (RNE)
  unsigned r;
  asm("v_cvt_pk_bf16_f32 %0, %1, %2" : "=v"(r) : "v"(lo), "v"(hi));
  return r;
}

DEVI float exp2v(float x) {  // 2^x via v_exp_f32
  float y;
  asm("v_exp_f32 %0, %1" : "=v"(y) : "v"(x));
  return y;
}

DEVI void gload_lds16(const void* g, void* l) {
  __builtin_amdgcn_global_load_lds((__attribute__((address_space(1))) void*)g,
                                   (__attribute__((address_space(3))) void*)l, 16, 0, 0);
}

#define WAIT_VM(N) asm volatile("s_waitcnt vmcnt(" #N ")" ::: "memory")
#define BARRIER __builtin_amdgcn_s_barrier()

constexpr int MD = 1024;
constexpr int NH = 16;
constexpr int HD = 64;
constexpr int LL = 2048;
// fold 1/sqrt(64) * log2(e) into Q so softmax runs in exp2 domain
constexpr float CQ = 0.18033688011112042f;

// ---------------- fused fp32 -> bf16 weight convert (4 x 1M elems) -------------
struct Cvt4Args { const float* src[4]; unsigned short* dst[4]; };

__global__ void cvt4_kernel(Cvt4Args a) {
  const int which = blockIdx.x >> 9;              // 512 blocks per matrix
  const int i = ((blockIdx.x & 511) * 256 + threadIdx.x) * 8;
  const float* w = a.src[which];
  unsigned short* o = a.dst[which];
  f32x4 x = *(const f32x4*)(w + i);
  f32x4 y = *(const f32x4*)(w + i + 4);
  union { unsigned u[4]; u32x4 q; } r;
  r.u[0] = cvtpk(x[0], x[1]); r.u[1] = cvtpk(x[2], x[3]);
  r.u[2] = cvtpk(y[0], y[1]); r.u[3] = cvtpk(y[2], y[3]);
  *(u32x4*)(o + i) = r.q;
}

// ---------------- fused QKV GEMM: C = A W^T + b --------------------------------
// mode 0: Q -> Qh[b][h][l][d], scaled by CQ
// mode 1: K -> Kh[b][h][l][d]
// mode 2: V -> Vt[b][h][d][l]  (transposed for attention PV)
struct QKVArgs {
  const float* A[3];
  const unsigned short* W[3];
  const float* bias[3];
  unsigned short* out[3];
};

__global__ __launch_bounds__(256, 2) void gemm_qkv(QKVArgs args) {
  // A fp32 [128][32], rows of 128B = 8 slots of 16B, slot ^= (row&7)  (T2/rule21)
  __shared__ alignas(16) float Afl[2][128 * 32];
  // W bf16 [128][32], rows of 64B = 4 slots of 16B, slot ^= ((row>>1)&3)
  __shared__ alignas(16) unsigned short Bl[2][128 * 32];

  const int tid = threadIdx.x;
  const int lane = tid & 63;
  const int wave = tid >> 6;
  const int wr = wave >> 1, wc = wave & 1;
  const int lr = lane & 15, lg = lane >> 4;

  // XCD-aware swizzle: 768 blocks = 8 XCDs x 96; n fastest within a chunk
  const int logical = (int)(blockIdx.x & 7) * 96 + (int)(blockIdx.x >> 3);
  const int n0 = (logical & 7) * 128;
  const int y = logical >> 3;          // 0..95
  const int mode = y >> 5;
  const int m0 = (y & 31) * 128;

  const float* Af = args.A[mode];
  const unsigned short* Wb = args.W[mode];
  const float* bias = args.bias[mode];
  unsigned short* Out = args.out[mode];

  const int arow_l = lane >> 3, aslot = lane & 7;   // A DMA mapping (8 slots/row)
  const int wrow_l = lane >> 2, wslot = lane & 3;   // W DMA mapping (4 slots/row)

  f32x4 acc[4][4] = {};

  auto stage = [&](int b, int kt) {
    const int k0 = kt * 32;
    #pragma unroll
    for (int sh = 0; sh < 4; ++sh) {                 // A: 16KB = 4 wave-shots
      const int row = sh * 32 + wave * 8 + arow_l;
      const int ss = aslot ^ (row & 7);              // pre-swizzled source
      gload_lds16((const char*)(Af + (size_t)(m0 + row) * 1024 + k0) + ss * 16,
                  (char*)&Afl[b][0] + sh * 4096 + wave * 1024);
    }
    #pragma unroll
    for (int sh = 0; sh < 2; ++sh) {                 // W: 8KB = 2 wave-shots
      const int row = sh * 64 + wave * 16 + wrow_l;
      const int ss = wslot ^ ((row >> 1) & 3);
      gload_lds16((const char*)(Wb + (size_t)(n0 + row) * 1024 + k0) + ss * 16,
                  (char*)&Bl[b][0] + sh * 4096 + wave * 1024);
    }
  };

  stage(0, 0);   // prologue

  for (int kt = 0; kt < 32; ++kt) {
    const int buf = kt & 1;
    if (kt < 31) {
      stage(buf ^ 1, kt + 1);   // queue: [t x6, (t+1) x6]
      WAIT_VM(6);               // tile t landed; t+1's 6 ride across the barrier
    } else {
      WAIT_VM(0);
    }
    BARRIER;

    // A fragments: row = wr*64+mi*16+lr, k-cols lg*8..+7 (fp32 -> bf16 here)
    bf16x8 af[4], bfr[4];
    #pragma unroll
    for (int mi = 0; mi < 4; ++mi) {
      const int row = wr * 64 + mi * 16 + lr;
      const char* base = (const char*)&Afl[buf][0] + row * 128;
      f32x4 a0 = *(const f32x4*)(base + ((((unsigned)lg * 2)     ^ (row & 7)) << 4));
      f32x4 a1 = *(const f32x4*)(base + ((((unsigned)lg * 2 + 1) ^ (row & 7)) << 4));
      union { unsigned u[4]; bf16x8 v; } t;
      t.u[0] = cvtpk(a0[0], a0[1]); t.u[1] = cvtpk(a0[2], a0[3]);
      t.u[2] = cvtpk(a1[0], a1[1]); t.u[3] = cvtpk(a1[2], a1[3]);
      af[mi] = t.v;
    }
    #pragma unroll
    for (int ni = 0; ni < 4; ++ni) {
      const int row = wc * 64 + ni * 16 + lr;
      bfr[ni] = *(const bf16x8*)((const char*)&Bl[buf][0] + row * 64 +
                                 (((unsigned)lg ^ ((row >> 1) & 3)) << 4));
    }

    __builtin_amdgcn_s_setprio(1);
    #pragma unroll
    for (int mi = 0; mi < 4; ++mi)
      #pragma unroll
      for (int ni = 0; ni < 4; ++ni)
        acc[mi][ni] = __builtin_amdgcn_mfma_f32_16x16x32_bf16(af[mi], bfr[ni], acc[mi][ni], 0, 0, 0);
    __builtin_amdgcn_s_setprio(0);
    BARRIER;                    // all LDS reads of buf done before re-staging
  }

  float bv[4];
  const int cn = n0 + wc * 64 + lr;
  #pragma unroll
  for (int ni = 0; ni < 4; ++ni) bv[ni] = bias[cn + ni * 16];

  #pragma unroll
  for (int mi = 0; mi < 4; ++mi) {
    #pragma unroll
    for (int j = 0; j < 4; ++j) {
      const int m = m0 + wr * 64 + mi * 16 + lg * 4 + j;
      const int b = m >> 11, l = m & 2047;
      #pragma unroll
      for (int ni = 0; ni < 4; ++ni) {
        const int n = cn + ni * 16;
        const int h = n >> 6, d = n & 63;
        float val = acc[mi][ni][j] + bv[ni];
        if (mode == 0) val *= CQ;
        if (mode == 2)
          Out[((size_t)(b * NH + h) * HD + d) * LL + l] = f2bf(val);
        else
          Out[((size_t)(b * NH + h) * LL + l) * HD + d] = f2bf(val);
      }
    }
  }
}

// ---------------- output GEMM: d_out = ctx Wo^T + bo (A bf16, out fp32) --------
__global__ __launch_bounds__(256, 2) void gemm_out(const unsigned short* __restrict__ Ab,
                                                   const unsigned short* __restrict__ Wb,
                                                   const float* __restrict__ bias,
                                                   float* __restrict__ Out) {
  __shared__ alignas(16) unsigned short Al[2][128 * 32];
  __shared__ alignas(16) unsigned short Bl[2][128 * 32];

  const int tid = threadIdx.x;
  const int lane = tid & 63;
  const int wave = tid >> 6;
  const int wr = wave >> 1, wc = wave & 1;
  const int lr = lane & 15, lg = lane >> 4;

  // XCD swizzle: 256 blocks = 8 x 32
  const int logical = (int)(blockIdx.x & 7) * 32 + (int)(blockIdx.x >> 3);
  const int n0 = (logical & 7) * 128;
  const int m0 = (logical >> 3) * 128;

  const int wrow = tid >> 2, wslot = tid & 3;

  f32x4 acc[4][4] = {};

  auto stage = [&](int b, int kt, const unsigned short* src, unsigned short* dstbase) {
    const int k0 = kt * 32;
    #pragma unroll
    for (int shot = 0; shot < 2; ++shot) {
      const int row = shot * 64 + wrow;
      const int ss = wslot ^ ((row >> 1) & 3);
      gload_lds16((const char*)(src + (size_t)row * 1024 + k0) + ss * 16,
                  (char*)dstbase + shot * 4096 + wave * 1024);
    }
  };

  stage(0, 0, Ab + (size_t)m0 * 1024, &Al[0][0]);
  stage(0, 0, Wb + (size_t)n0 * 1024, &Bl[0][0]);

  for (int kt = 0; kt < 32; ++kt) {
    const int buf = kt & 1;
    if (kt < 31) {
      stage(buf ^ 1, kt + 1, Ab + (size_t)m0 * 1024, &Al[buf ^ 1][0]);
      stage(buf ^ 1, kt + 1, Wb + (size_t)n0 * 1024, &Bl[buf ^ 1][0]);
      WAIT_VM(4);              // tile t landed; t+1's 4 ops stay in flight
    } else {
      WAIT_VM(0);
    }
    BARRIER;

    bf16x8 af[4], bfr[4];
    #pragma unroll
    for (int mi = 0; mi < 4; ++mi) {
      const int row = wr * 64 + mi * 16 + lr;
      af[mi] = *(const bf16x8*)((const char*)&Al[buf][0] + row * 64 +
                                (((unsigned)lg ^ ((row >> 1) & 3)) << 4));
    }
    #pragma unroll
    for (int ni = 0; ni < 4; ++ni) {
      const int row = wc * 64 + ni * 16 + lr;
      bfr[ni] = *(const bf16x8*)((const char*)&Bl[buf][0] + row * 64 +
                                 (((unsigned)lg ^ ((row >> 1) & 3)) << 4));
    }
    __builtin_amdgcn_s_setprio(1);
    #pragma unroll
    for (int mi = 0; mi < 4; ++mi)
      #pragma unroll
      for (int ni = 0; ni < 4; ++ni)
        acc[mi][ni] = __builtin_amdgcn_mfma_f32_16x16x32_bf16(af[mi], bfr[ni], acc[mi][ni], 0, 0, 0);
    __builtin_amdgcn_s_setprio(0);
    BARRIER;                   // all reads of buf done before next-iter staging
  }

  float bv[4];
  const int cn = n0 + wc * 64 + lr;
  #pragma unroll
  for (int ni = 0; ni < 4; ++ni) bv[ni] = bias[cn + ni * 16];

  #pragma unroll
  for (int mi = 0; mi < 4; ++mi)
    #pragma unroll
    for (int j = 0; j < 4; ++j) {
      const int m = m0 + wr * 64 + mi * 16 + lg * 4 + j;
      #pragma unroll
      for (int ni = 0; ni < 4; ++ni)
        Out[(size_t)m * 1024 + cn + ni * 16] = acc[mi][ni][j] + bv[ni];
    }
}

// ---------------- flash attention: swapped-QK 32x32, in-register softmax -------
// 512 blocks (XCD-swizzled). 4 waves x 32 q-rows. KB=64 double-buffered LDS.
__global__ __launch_bounds__(256, 2) void attn_kernel(const unsigned short* __restrict__ Qh,
                                                      const unsigned short* __restrict__ Kh,
                                                      const unsigned short* __restrict__ Vt,
                                                      unsigned short* __restrict__ Ctx) {
  constexpr int KB = 64;
  constexpr int NT = LL / KB;  // 32
  __shared__ alignas(16) unsigned short Kl[2][KB * HD];   // [kv][d], XOR-swizzled
  __shared__ alignas(16) unsigned short Vl[2][HD * KB];   // [d][kv], XOR-swizzled

  const int tid = threadIdx.x;
  const int lane = tid & 63;
  const int wave = tid >> 6;
  const int lq = lane & 31;
  const int hi = lane >> 5;

  // XCD swizzle: 512 blocks = 8 x 64; q-block fastest within a chunk
  const int logical = (int)(blockIdx.x & 7) * 64 + (int)(blockIdx.x >> 3);
  const int bh = logical >> 4;
  const int q0 = (logical & 15) * 128 + wave * 32;

  const unsigned short* Kg = Kh + (size_t)bh * LL * HD;
  const unsigned short* Vg = Vt + (size_t)bh * HD * LL;

  bf16x8 qf[4];
  {
    const unsigned short* qp = Qh + (size_t)bh * LL * HD + (size_t)(q0 + lq) * HD + hi * 8;
    #pragma unroll
    for (int s = 0; s < 4; ++s) qf[s] = *(const bf16x8*)(qp + s * 16);
  }

  f32x16 oacc0 = {}, oacc1 = {};   // O^T: d rows 0..31 / 32..63, col = q
  float m_ = -1e30f, s_ = 0.f;     // per-lane (per-q) stats, exp2 domain

  auto stage = [&](int b, int t) {
    #pragma unroll
    for (int shot = 0; shot < 2; ++shot) {
      const int o = shot * 4096 + tid * 16;
      const int row = o >> 7, col = o & 127;
      const int sc = col ^ ((row & 7) << 4);           // pre-swizzled source (T2)
      gload_lds16((const char*)Kg + (size_t)(t * KB + row) * (HD * 2) + sc,
                  (char*)&Kl[b][0] + shot * 4096 + wave * 1024);
    }
    #pragma unroll
    for (int shot = 0; shot < 2; ++shot) {
      const int o = shot * 4096 + tid * 16;
      const int row = o >> 7, col = o & 127;
      const int sc = col ^ ((row & 7) << 4);
      gload_lds16((const char*)Vg + (size_t)row * (LL * 2) + t * (KB * 2) + sc,
                  (char*)&Vl[b][0] + shot * 4096 + wave * 1024);
    }
  };

  stage(0, 0);

  for (int t = 0; t < NT; ++t) {
    const int buf = t & 1;
    if (t + 1 < NT) {
      stage(buf ^ 1, t + 1);   // 4 more in flight
      WAIT_VM(4);              // tile t staged; t+1 rides across the barrier
    } else {
      WAIT_VM(0);
    }
    BARRIER;

    // ---- S^T = K . Q : two 32x32 tiles over kv
    f32x16 st0 = {}, st1 = {};
    const int swz = (lq & 7) << 4;
    __builtin_amdgcn_s_setprio(1);
    #pragma unroll
    for (int s = 0; s < 4; ++s) {
      const int off = ((s * 32 + hi * 16) ^ swz);
      bf16x8 k0 = *(const bf16x8*)((const char*)&Kl[buf][0] + lq * 128 + off);
      bf16x8 k1 = *(const bf16x8*)((const char*)&Kl[buf][0] + (32 + lq) * 128 + off);
      st0 = __builtin_amdgcn_mfma_f32_32x32x16_bf16(k0, qf[s], st0, 0, 0, 0);
      st1 = __builtin_amdgcn_mfma_f32_32x32x16_bf16(k1, qf[s], st1, 0, 0, 0);
    }
    __builtin_amdgcn_s_setprio(0);

    // ---- in-register row max + cross-half combine
    float tv[8];
    #pragma unroll
    for (int i = 0; i < 8; ++i)
      tv[i] = fmaxf(fmaxf(st0[i], st0[i + 8]), fmaxf(st1[i], st1[i + 8]));
    float pmax = fmaxf(fmaxf(fmaxf(tv[0], tv[1]), fmaxf(tv[2], tv[3])),
                       fmaxf(fmaxf(tv[4], tv[5]), fmaxf(tv[6], tv[7])));
    pmax = fmaxf(pmax, __shfl_xor(pmax, 32));

    // ---- defer-max rescale (T13, THR=8 in log2 units)
    if (!__all(pmax - m_ <= 8.f)) {
      const float nm = fmaxf(m_, pmax);
      const float al = exp2v(m_ - nm);
      m_ = nm;
      s_ *= al;
      #pragma unroll
      for (int i = 0; i < 16; ++i) { oacc0[i] *= al; oacc1[i] *= al; }
    }

    // ---- P = exp2(S' - m) in place + lane-local partial sum
    float a4[4] = {0.f, 0.f, 0.f, 0.f};
    #pragma unroll
    for (int i = 0; i < 16; ++i) {
      float y0 = exp2v(st0[i] - m_);
      float y1 = exp2v(st1[i] - m_);
      st0[i] = y0; st1[i] = y1;
      a4[i & 3] += y0; a4[i & 3] += y1;
    }
    s_ += (a4[0] + a4[1]) + (a4[2] + a4[3]);

    // ---- build P^T B-fragments (cvt_pk + cross-half shfl)
    bf16x8 pfr[4];
    #pragma unroll
    for (int s = 0; s < 4; ++s) {
      const int r = (s & 1) * 8;
      float p0, p1, p2, p3, p4, p5, p6, p7;
      if (s < 2) {
        p0 = st0[r+0]; p1 = st0[r+1]; p2 = st0[r+2]; p3 = st0[r+3];
        p4 = st0[r+4]; p5 = st0[r+5]; p6 = st0[r+6]; p7 = st0[r+7];
      } else {
        p0 = st1[r+0]; p1 = st1[r+1]; p2 = st1[r+2]; p3 = st1[r+3];
        p4 = st1[r+4]; p5 = st1[r+5]; p6 = st1[r+6]; p7 = st1[r+7];
      }
      const unsigned A0 = cvtpk(p0, p1);
      const unsigned A1 = cvtpk(p2, p3);
      const unsigned A2 = cvtpk(p4, p5);
      const unsigned A3 = cvtpk(p6, p7);
      const unsigned t0 = (unsigned)__shfl_xor((int)A0, 32);
      const unsigned t1 = (unsigned)__shfl_xor((int)A1, 32);
      const unsigned t2 = (unsigned)__shfl_xor((int)A2, 32);
      const unsigned t3 = (unsigned)__shfl_xor((int)A3, 32);
      union { unsigned u[4]; bf16x8 v; } pf;
      pf.u[0] = hi ? t2 : A0;
      pf.u[1] = hi ? t3 : A1;
      pf.u[2] = hi ? A2 : t0;
      pf.u[3] = hi ? A3 : t1;
      pfr[s] = pf.v;
    }

    // ---- O^T += V^T . P^T
    __builtin_amdgcn_s_setprio(1);
    #pragma unroll
    for (int s = 0; s < 4; ++s) {
      const int off = ((s * 32 + hi * 16) ^ swz);
      bf16x8 v0 = *(const bf16x8*)((const char*)&Vl[buf][0] + lq * 128 + off);
      bf16x8 v1 = *(const bf16x8*)((const char*)&Vl[buf][0] + (32 + lq) * 128 + off);
      oacc0 = __builtin_amdgcn_mfma_f32_32x32x16_bf16(v0, pfr[s], oacc0, 0, 0, 0);
      oacc1 = __builtin_amdgcn_mfma_f32_32x32x16_bf16(v1, pfr[s], oacc1, 0, 0, 0);
    }
    __builtin_amdgcn_s_setprio(0);
    BARRIER;                   // all reads of buf done before next-iter staging
  }

  // ---- finalize
  s_ += __shfl_xor(s_, 32);
  const float inv = 1.0f / s_;
  const int b = bh >> 4, h = bh & 15;
  const int q = q0 + lq;
  unsigned short* op = Ctx + ((size_t)(b * LL + q)) * MD + h * HD;
  #pragma unroll
  for (int g = 0; g < 4; ++g) {
    {
      union { unsigned short us[4]; u32x2 u; } w;
      #pragma unroll
      for (int j = 0; j < 4; ++j) w.us[j] = f2bf(oacc0[g * 4 + j] * inv);
      *(u32x2*)(op + 8 * g + 4 * hi) = w.u;
    }
    {
      union { unsigned short us[4]; u32x2 u; } w;
      #pragma unroll
      for (int j = 0; j < 4; ++j) w.us[j] = f2bf(oacc1[g * 4 + j] * inv);
      *(u32x2*)(op + 32 + 8 * g + 4 * hi) = w.u;
    }
  }
}

extern "C" void kernel_launch(void* const* d_in, const int* in_sizes, int n_in,
                              void* d_out, int out_size, void* d_ws, size_t ws_size,
                              hipStream_t stream) {
  const float* q  = (const float*)d_in[0];
  const float* k  = (const float*)d_in[1];
  const float* v  = (const float*)d_in[2];
  const float* Wq = (const float*)d_in[3];
  const float* bq = (const float*)d_in[4];
  const float* Wk = (const float*)d_in[5];
  const float* bk = (const float*)d_in[6];
  const float* Wv = (const float*)d_in[7];
  const float* bv = (const float*)d_in[8];
  const float* Wo = (const float*)d_in[9];
  const float* bo = (const float*)d_in[10];

  char* ws = (char*)d_ws;
  const size_t MB = 1u << 20;
  unsigned short* Wqb = (unsigned short*)(ws + 0 * MB);
  unsigned short* Wkb = (unsigned short*)(ws + 2 * MB);
  unsigned short* Wvb = (unsigned short*)(ws + 4 * MB);
  unsigned short* Wob = (unsigned short*)(ws + 6 * MB);
  unsigned short* Qhb = (unsigned short*)(ws + 8 * MB);
  unsigned short* Khb = (unsigned short*)(ws + 16 * MB);
  unsigned short* Vtb = (unsigned short*)(ws + 24 * MB);
  unsigned short* ctx = (unsigned short*)(ws + 32 * MB);

  Cvt4Args ca;
  ca.src[0] = Wq; ca.src[1] = Wk; ca.src[2] = Wv; ca.src[3] = Wo;
  ca.dst[0] = Wqb; ca.dst[1] = Wkb; ca.dst[2] = Wvb; ca.dst[3] = Wob;
  cvt4_kernel<<<2048, 256, 0, stream>>>(ca);

  QKVArgs args;
  args.A[0] = q;  args.A[1] = k;  args.A[2] = v;
  args.W[0] = Wqb; args.W[1] = Wkb; args.W[2] = Wvb;
  args.bias[0] = bq; args.bias[1] = bk; args.bias[2] = bv;
  args.out[0] = Qhb; args.out[1] = Khb; args.out[2] = Vtb;
  gemm_qkv<<<768, 256, 0, stream>>>(args);

  attn_kernel<<<512, 256, 0, stream>>>(Qhb, Khb, Vtb, ctx);

  gemm_out<<<256, 256, 0, stream>>>(ctx, Wob, bo, (float*)d_out);
}